// Round 10
// baseline (874.092 us; speedup 1.0000x reference)
//
#include <hip/hip_runtime.h>
#include <hip/hip_fp16.h>

#define N_NODES 50000
#define N_EDGES 800000
#define DIM 128
#define NODE_TILES 782   // ceil(50000/64)
#define EDGE_TILES 12500 // 800000/64
#define EA_BLOCKS 2500
#define EA_PERBLK 5      // EA_BLOCKS * EA_PERBLK == EDGE_TILES

typedef _Float16 f16;
typedef _Float16 f16x2 __attribute__((ext_vector_type(2)));
typedef _Float16 f16x4 __attribute__((ext_vector_type(4)));
typedef _Float16 f16x8 __attribute__((ext_vector_type(8)));
typedef float    f32x16 __attribute__((ext_vector_type(16)));

__device__ __forceinline__ void sfence() { __builtin_amdgcn_sched_barrier(0); }

// ---------------- shared GEMM pieces ----------------
__device__ __forceinline__ void load_wfrag(const f16* __restrict__ Wh, int ch, int l31, int g,
                                           f16x8 bf[2][8]) {
#pragma unroll
  for (int c = 0; c < 2; ++c)
#pragma unroll
    for (int ks = 0; ks < 8; ++ks)
      bf[c][ks] = *(const f16x8*)(Wh + ((ch * 64 + c * 32 + l31) << 7) + 16 * ks + 8 * g);
}

template <int HALF_OUT, int SILU>
__device__ __forceinline__ void gemm_store(f32x16 acc[2], long M, const float* __restrict__ Bv,
                                           void* __restrict__ OUT,
                                           long tile0, int rc, int ch, int l31, int g) {
#pragma unroll
  for (int c = 0; c < 2; ++c) {
    int col = ch * 64 + c * 32 + l31;
    float bv = Bv[col];
#pragma unroll
    for (int r = 0; r < 16; ++r) {
      long gm = tile0 + rc * 32 + ((r & 3) + 8 * (r >> 2) + 4 * g);
      if (gm < M) {
        float v = acc[c][r] + bv;
        if (SILU) v = v / (1.0f + __expf(-v));
        if (HALF_OUT) ((f16*)OUT)[gm * DIM + col] = (f16)v;
        else          ((float*)OUT)[gm * DIM + col] = v;
      }
    }
  }
}

// ---------------- staging: coalesced, f32->f16, XOR-swizzled LDS ----------------
__device__ __forceinline__ void stage_issue(const float* __restrict__ X, long M, long base,
                                            int tid, float4 sv[8]) {
#pragma unroll
  for (int kk = 0; kk < 8; ++kk) {
    int i = tid + kk * 256;            // [0, 2048): 64 rows x 32 slots of 16B(f32)
    long row = base + (i >> 5);
    long gr = row < M ? row : (M - 1);
    sv[kk] = *(const float4*)(X + gr * DIM + (i & 31) * 4);   // fully coalesced
  }
}

// gather variant: tile rows are elist[base..base+64) (dst-sorted edge order)
__device__ __forceinline__ void stage_issue_g(const float* __restrict__ X,
                                              const int* __restrict__ elist, long base,
                                              int tid, float4 sv[8]) {
#pragma unroll
  for (int kk = 0; kk < 8; ++kk) {
    int i = tid + kk * 256;
    int eid = elist[base + (i >> 5)];      // L2-hot, broadcast within 32-thread group
    sv[kk] = *(const float4*)(X + (long)eid * DIM + (i & 31) * 4);  // full 512B row segs
  }
}

__device__ __forceinline__ void stage_write(const float4 sv[8], int tid, f16* __restrict__ lds) {
#pragma unroll
  for (int kk = 0; kk < 8; ++kk) {
    int i = tid + kk * 256;
    int r = i >> 5, s8 = i & 31;
    f16x4 h;
    h[0] = (f16)sv[kk].x; h[1] = (f16)sv[kk].y; h[2] = (f16)sv[kk].z; h[3] = (f16)sv[kk].w;
    *(f16x4*)(lds + r * 128 + (((s8 >> 1) ^ (r & 15)) << 3) + ((s8 & 1) << 2)) = h;
  }
}

// gemm over LDS tile
__device__ __forceinline__ void mfma_lds_g(const f16* __restrict__ A, int lr, int g,
                                           const f16x8 bf[2][8], f32x16 acc[2]) {
#pragma unroll
  for (int c = 0; c < 2; ++c)
#pragma unroll
    for (int k = 0; k < 16; ++k) acc[c][k] = 0.0f;
#pragma unroll
  for (int ks = 0; ks < 8; ++ks) {
    f16x8 a = *(const f16x8*)(A + lr * 128 + (((2 * ks + g) ^ (lr & 15)) << 3));
    acc[0] = __builtin_amdgcn_mfma_f32_32x32x16_f16(a, bf[0][ks], acc[0], 0, 0, 0);
    acc[1] = __builtin_amdgcn_mfma_f32_32x32x16_f16(a, bf[1][ks], acc[1], 0, 0, 0);
  }
}

// ---------------- GEMM v4 (sequential rows), double-buffered ----------------
template <int HALF_OUT, int SILU>
__global__ __launch_bounds__(256) void gemm_v4(const float* __restrict__ X, long M, int ntiles,
                                               const f16* __restrict__ Wh,
                                               const float* __restrict__ Bv,
                                               void* __restrict__ OUT) {
  __shared__ f16 lbuf[2][64 * 128];
  int tid = threadIdx.x;
  int lane = tid & 63, w = tid >> 6;
  int rc = w >> 1, ch = w & 1, l31 = lane & 31, g = lane >> 5;
  int t0 = blockIdx.x;
  if (t0 >= ntiles) return;
  f16x8 bf[2][8];
  load_wfrag(Wh, ch, l31, g, bf);
  float4 sv[8];
  stage_issue(X, M, (long)t0 * 64, tid, sv);
  stage_write(sv, tid, lbuf[0]);
  __syncthreads();
  int cur = 0;
  int lr = rc * 32 + l31;
  for (int t = t0; t < ntiles; t += gridDim.x) {
    int tn = t + gridDim.x;
    if (tn < ntiles) stage_issue(X, M, (long)tn * 64, tid, sv);
    sfence();
    f32x16 acc[2];
    mfma_lds_g(lbuf[cur], lr, g, bf, acc);
    gemm_store<HALF_OUT, SILU>(acc, M, Bv, OUT, (long)t * 64, rc, ch, l31, g);
    if (tn < ntiles) {
      asm volatile("s_waitcnt vmcnt(0)" ::: "memory");
      stage_write(sv, tid, lbuf[cur ^ 1]);
    }
    __syncthreads();
    cur ^= 1;
  }
}

// ---------------- node4 v4: X-tile staged once, 4 weight mats ----------------
__global__ __launch_bounds__(256) void node4_v4(const float* __restrict__ X,
    const f16* __restrict__ WhAll,
    const float* __restrict__ bq, const float* __restrict__ bk,
    const float* __restrict__ bv_, const float* __restrict__ bs,
    f16* __restrict__ Q, f16* __restrict__ K, f16* __restrict__ V, float* __restrict__ S) {
  __shared__ f16 xs[64 * 128];
  int tid = threadIdx.x;
  int lane = tid & 63, w = tid >> 6;
  int rc = w >> 1, ch = w & 1, l31 = lane & 31, g = lane >> 5;
  int t = blockIdx.x;
  if (t >= NODE_TILES) return;
  long tile0 = (long)t * 64;
  float4 sv[8];
  stage_issue(X, N_NODES, tile0, tid, sv);
  stage_write(sv, tid, xs);
  __syncthreads();
  int lr = rc * 32 + l31;
#pragma unroll 1
  for (int mat = 0; mat < 4; ++mat) {
    f16x8 bf[2][8];
    load_wfrag(WhAll + mat * 16384, ch, l31, g, bf);
    f32x16 acc[2];
    mfma_lds_g(xs, lr, g, bf, acc);
    if (mat == 0)      gemm_store<1, 0>(acc, N_NODES, bq, Q, tile0, rc, ch, l31, g);
    else if (mat == 1) gemm_store<1, 0>(acc, N_NODES, bk, K, tile0, rc, ch, l31, g);
    else if (mat == 2) gemm_store<1, 0>(acc, N_NODES, bv_, V, tile0, rc, ch, l31, g);
    else               gemm_store<0, 0>(acc, N_NODES, bs, S, tile0, rc, ch, l31, g);
  }
}

// ---------------- fused edge-GEMM + attention v3: persistent + pipelined ----------------
// 2500 blocks x 5 consecutive 64-edge tiles. Per iter: write staged regs->LDS, MFMA,
// issue NEXT tile's cluster (EA gather + K/V + meta), then alpha/exp/atomics of the
// current tile (next tile's HBM latency hides under this VALU phase).
__global__ __launch_bounds__(256) void edge_attn(const float* __restrict__ EA,
    const int* __restrict__ elist, const int* __restrict__ srcs, const int* __restrict__ dsts,
    const f16* __restrict__ WeH, const float* __restrict__ be,
    const f16* __restrict__ Qn, const f16* __restrict__ Kn, const f16* __restrict__ Vn,
    float* __restrict__ AS, float* __restrict__ DEN) {
  __shared__ f16 stg[64 * 128];      // 16 KB (EA tile, swizzled)
  __shared__ f16 klds[64 * 136];     // 17 KB (K[src], padded rows)
  __shared__ f16 vlds[64 * 136];     // 17 KB (V[src], padded rows)
  __shared__ int smeta[64];          // dst per row
  int tid = threadIdx.x;
  int lane = tid & 63, w = tid >> 6;
  int rc = w >> 1, ch = w & 1, l31 = lane & 31, g = lane >> 5;
  int lr = rc * 32 + l31;

  f16x8 bf[2][8];
  load_wfrag(WeH, ch, l31, g, bf);
  float bcol[2] = { be[ch * 64 + l31], be[ch * 64 + 32 + l31] };

  long pos0 = (long)blockIdx.x * (EA_PERBLK * 64);

  float4 sv[8]; f16x8 kv[4], vv[4]; int mreg = 0;
  stage_issue_g(EA, elist, pos0, tid, sv);
#pragma unroll
  for (int k = 0; k < 4; ++k) {
    int i = tid + k * 256;                 // 1024 units: 64 rows x 16 slots of 16B
    int row = i >> 4, slot = i & 15;
    int s = srcs[pos0 + row];
    kv[k] = *(const f16x8*)(Kn + (long)s * DIM + slot * 8);
    vv[k] = *(const f16x8*)(Vn + (long)s * DIM + slot * 8);
  }
  if (tid < 64) mreg = dsts[pos0 + tid];

  for (int t = 0; t < EA_PERBLK; ++t) {
    long pos = pos0 + (long)t * 64;
    // ---- drain staged regs into LDS (waits only on this tile's loads) ----
    stage_write(sv, tid, stg);
#pragma unroll
    for (int k = 0; k < 4; ++k) {
      int i = tid + k * 256;
      int row = i >> 4, slot = i & 15;
      *(f16x8*)(klds + row * 136 + slot * 8) = kv[k];
      *(f16x8*)(vlds + row * 136 + slot * 8) = vv[k];
    }
    if (tid < 64) smeta[tid] = mreg;
    __syncthreads();

    f32x16 acc[2];
    mfma_lds_g(stg, lr, g, bf, acc);

    // ---- prefetch next tile; lands during the alpha phase below ----
    if (t + 1 < EA_PERBLK) {
      long pn = pos + 64;
      stage_issue_g(EA, elist, pn, tid, sv);
#pragma unroll
      for (int k = 0; k < 4; ++k) {
        int i = tid + k * 256;
        int row = i >> 4, slot = i & 15;
        int s = srcs[pn + row];
        kv[k] = *(const f16x8*)(Kn + (long)s * DIM + slot * 8);
        vv[k] = *(const f16x8*)(Vn + (long)s * DIM + slot * 8);
      }
      if (tid < 64) mreg = dsts[pn + tid];
    }
    sfence();

    // ---- alpha + online weighted sum, run-accumulated over sorted dst ----
    int col0 = ch * 64 + l31, col1 = col0 + 32;
    bool denlane = (l31 & 15) == 0;
    int h0 = col0 >> 4, h1 = col1 >> 4;
    float as0 = 0.f, as1 = 0.f, dn0 = 0.f, dn1 = 0.f;
    int dprev = smeta[rc * 32 + 4 * g];
    float q0 = (float)Qn[(long)dprev * DIM + col0];
    float q1 = (float)Qn[(long)dprev * DIM + col1];
#pragma unroll
    for (int r = 0; r < 16; ++r) {
      int row = rc * 32 + (r & 3) + 8 * (r >> 2) + 4 * g;
      int d = smeta[row];
      if (d != dprev) {
        atomicAdd(&AS[(long)dprev * DIM + col0], as0);
        atomicAdd(&AS[(long)dprev * DIM + col1], as1);
        if (denlane) {
          atomicAdd(&DEN[(long)dprev * 8 + h0], dn0);
          atomicAdd(&DEN[(long)dprev * 8 + h1], dn1);
        }
        as0 = as1 = dn0 = dn1 = 0.f;
        dprev = d;
        q0 = (float)Qn[(long)d * DIM + col0];
        q1 = (float)Qn[(long)d * DIM + col1];
      }
      {
        float ev = acc[0][r] + bcol[0];
        float ke = (float)klds[row * 136 + col0] + ev;
        float ve = (float)vlds[row * 136 + col0] + ev;
        float p = q0 * ke;
        p += __shfl_xor(p, 1); p += __shfl_xor(p, 2);
        p += __shfl_xor(p, 4); p += __shfl_xor(p, 8);
        float ex = __expf(p * 0.25f);
        as0 += ex * ve; dn0 += ex;
      }
      {
        float ev = acc[1][r] + bcol[1];
        float ke = (float)klds[row * 136 + col1] + ev;
        float ve = (float)vlds[row * 136 + col1] + ev;
        float p = q1 * ke;
        p += __shfl_xor(p, 1); p += __shfl_xor(p, 2);
        p += __shfl_xor(p, 4); p += __shfl_xor(p, 8);
        float ex = __expf(p * 0.25f);
        as1 += ex * ve; dn1 += ex;
      }
    }
    atomicAdd(&AS[(long)dprev * DIM + col0], as0);
    atomicAdd(&AS[(long)dprev * DIM + col1], as1);
    if (denlane) {
      atomicAdd(&DEN[(long)dprev * 8 + h0], dn0);
      atomicAdd(&DEN[(long)dprev * 8 + h1], dn1);
    }
    __syncthreads();   // all LDS reads done before next iter's stage_write
  }
}

// convert all 7 weight matrices f32 -> f16
__global__ void convert7(const float* __restrict__ a0, const float* __restrict__ a1,
                         const float* __restrict__ a2, const float* __restrict__ a3,
                         const float* __restrict__ a4, const float* __restrict__ a5,
                         const float* __restrict__ a6, f16* __restrict__ dst) {
  int i = blockIdx.x * blockDim.x + threadIdx.x;
  int mat = i >> 14, el = i & 16383;
  const float* s = (mat == 0) ? a0 : (mat == 1) ? a1 : (mat == 2) ? a2 : (mat == 3) ? a3
                 : (mat == 4) ? a4 : (mat == 5) ? a5 : a6;
  dst[i] = (f16)s[el];
}

// ---------------- CSR build ----------------
__global__ void hist_k(const int* __restrict__ ei, int* __restrict__ counts) {
  for (long e = blockIdx.x * (long)blockDim.x + threadIdx.x; e < N_EDGES;
       e += (long)gridDim.x * blockDim.x)
    atomicAdd(&counts[ei[N_EDGES + e]], 1);
}

__global__ __launch_bounds__(1024) void scan_k(const int* __restrict__ counts,
                                               int* __restrict__ offs, int* __restrict__ cursor) {
  __shared__ int sd[1024];
  int tid = threadIdx.x;
  const int CH = (N_NODES + 1023) / 1024;
  int i0 = tid * CH;
  int s = 0;
  for (int i = 0; i < CH; ++i) { int idx = i0 + i; if (idx < N_NODES) s += counts[idx]; }
  sd[tid] = s; __syncthreads();
  for (int off = 1; off < 1024; off <<= 1) {
    int v = (tid >= off) ? sd[tid - off] : 0;
    __syncthreads();
    sd[tid] += v;
    __syncthreads();
  }
  int run = sd[tid] - s;
  for (int i = 0; i < CH; ++i) {
    int idx = i0 + i;
    if (idx < N_NODES) { offs[idx] = run; cursor[idx] = run; run += counts[idx]; }
  }
  if (tid == 1023) offs[N_NODES] = run;
}

// scatter: elist[pos]=edge id; srcs/dsts[pos]=src/dst node of that edge
__global__ void scatter_k(const int* __restrict__ ei, int* __restrict__ cursor,
                          int* __restrict__ elist, int* __restrict__ srcs,
                          int* __restrict__ dsts) {
  for (long e = blockIdx.x * (long)blockDim.x + threadIdx.x; e < N_EDGES;
       e += (long)gridDim.x * blockDim.x) {
    int d = ei[N_EDGES + e];
    int pos = atomicAdd(&cursor[d], 1);
    elist[pos] = (int)e;
    srcs[pos] = ei[e];
    dsts[pos] = d;
  }
}

// node1 = base + LN(AS/den + Skip) * g + b   (softmax division folded in)
__global__ __launch_bounds__(256) void post_ln_div(const float* __restrict__ AS,
    const float* __restrict__ DEN, const float* __restrict__ Skip,
    const float* __restrict__ base, const float* __restrict__ g,
    const float* __restrict__ b, float* __restrict__ outp) {
  int n = blockIdx.x * 4 + (threadIdx.x >> 6);
  if (n >= N_NODES) return;
  int lane = threadIdx.x & 63;
  float inv = 1.f / (DEN[(long)n * 8 + (lane >> 3)] + 1e-16f);
  float2 x = *(const float2*)(AS + (long)n * DIM + 2 * lane);
  float2 sk = *(const float2*)(Skip + (long)n * DIM + 2 * lane);
  x.x = x.x * inv + sk.x;
  x.y = x.y * inv + sk.y;
  float sm = x.x + x.y;
  for (int m = 1; m < 64; m <<= 1) sm += __shfl_xor(sm, m);
  float mu = sm * (1.f / 128.f);
  float dx = x.x - mu, dy = x.y - mu;
  float ss = dx * dx + dy * dy;
  for (int m = 1; m < 64; m <<= 1) ss += __shfl_xor(ss, m);
  float r = rsqrtf(ss * (1.f / 128.f) + 1e-5f);
  float2 gg = *(const float2*)(g + 2 * lane);
  float2 bb = *(const float2*)(b + 2 * lane);
  float2 bs = *(const float2*)(base + (long)n * DIM + 2 * lane);
  float2 o;
  o.x = bs.x + dx * r * gg.x + bb.x;
  o.y = bs.y + dy * r * gg.y + bb.y;
  *(float2*)(outp + (long)n * DIM + 2 * lane) = o;
}

// out = base + LN(xa) * g + b
__global__ __launch_bounds__(256) void post_ln(const float* __restrict__ xa,
    const float* __restrict__ base, const float* __restrict__ g,
    const float* __restrict__ b, float* __restrict__ outp) {
  int n = blockIdx.x * 4 + (threadIdx.x >> 6);
  if (n >= N_NODES) return;
  int lane = threadIdx.x & 63;
  float2 x = *(const float2*)(xa + (long)n * DIM + 2 * lane);
  float sm = x.x + x.y;
  for (int m = 1; m < 64; m <<= 1) sm += __shfl_xor(sm, m);
  float mu = sm * (1.f / 128.f);
  float dx = x.x - mu, dy = x.y - mu;
  float ss = dx * dx + dy * dy;
  for (int m = 1; m < 64; m <<= 1) ss += __shfl_xor(ss, m);
  float r = rsqrtf(ss * (1.f / 128.f) + 1e-5f);
  float2 gg = *(const float2*)(g + 2 * lane);
  float2 bb = *(const float2*)(b + 2 * lane);
  float2 bs = *(const float2*)(base + (long)n * DIM + 2 * lane);
  float2 o;
  o.x = bs.x + dx * r * gg.x + bb.x;
  o.y = bs.y + dy * r * gg.y + bb.y;
  *(float2*)(outp + (long)n * DIM + 2 * lane) = o;
}

// ---------------- launch ----------------
extern "C" void kernel_launch(void* const* d_in, const int* in_sizes, int n_in,
                              void* d_out, int out_size, void* d_ws, size_t ws_size,
                              hipStream_t stream) {
  (void)in_sizes; (void)n_in; (void)out_size; (void)ws_size;
  const int*   ei  = (const int*)d_in[0];
  const float* x0  = (const float*)d_in[1];
  const float* ea  = (const float*)d_in[2];
  const float* Wq  = (const float*)d_in[3];  const float* bq = (const float*)d_in[4];
  const float* Wk  = (const float*)d_in[5];  const float* bk = (const float*)d_in[6];
  const float* Wv  = (const float*)d_in[7];  const float* bv = (const float*)d_in[8];
  const float* We  = (const float*)d_in[9];  const float* be = (const float*)d_in[10];
  const float* Wsk = (const float*)d_in[11]; const float* bsk = (const float*)d_in[12];
  const float* W1  = (const float*)d_in[13]; const float* b1 = (const float*)d_in[14];
  const float* W2  = (const float*)d_in[15]; const float* b2 = (const float*)d_in[16];
  const float* g1  = (const float*)d_in[17]; const float* lb1 = (const float*)d_in[18];
  const float* g2  = (const float*)d_in[19]; const float* lb2 = (const float*)d_in[20];

  char* ws = (char*)d_ws;
  f16*   Qn     = (f16*)(ws + 0);              // 12.8M
  f16*   Kn     = (f16*)(ws + 12800000L);      // 12.8M
  f16*   Vn     = (f16*)(ws + 25600000L);      // 12.8M
  float* Skip   = (float*)(ws + 38400000L);    // 25.6M -> 64000000
  int*   offs   = (int*)(ws + 64000000L);      // 200,192
  f16*   WhAll  = (f16*)(ws + 64200192L);      // 229,376 (overlays cursor, dead after CSR)
  int*   cursor = (int*)(ws + 64200192L);
  int*   counts = (int*)(ws + 64429568L);      // 200,000
  int*   elist  = (int*)(ws + 64629760L);      // 3.2M
  int*   srcs   = (int*)(ws + 67829760L);      // 3.2M
  int*   dsts   = (int*)(ws + 71029760L);      // 3.2M
  float* den    = (float*)(ws + 74229760L);    // 1.6M
  float* node1  = (float*)(ws + 75829760L);    // 25.6M -> 101,429,760
  float* hid    = (float*)(ws + 38400000L);    // reuse Skip (dead after post_ln_div)
  float* h2     = (float*)(ws + 0);            // reuse Qn/Kn (dead after edge_attn)
  float* attn   = (float*)d_out;               // atomic accumulation target; overwritten at end

  (void)hipMemsetAsync(counts, 0, N_NODES * sizeof(int), stream);
  (void)hipMemsetAsync(attn, 0, (size_t)N_NODES * DIM * sizeof(float), stream);
  (void)hipMemsetAsync(den, 0, (size_t)N_NODES * 8 * sizeof(float), stream);
  hist_k<<<1024, 256, 0, stream>>>(ei, counts);
  scan_k<<<1, 1024, 0, stream>>>(counts, offs, cursor);
  scatter_k<<<1024, 256, 0, stream>>>(ei, cursor, elist, srcs, dsts);
  convert7<<<112, 1024, 0, stream>>>(Wq, Wk, Wv, Wsk, We, W1, W2, WhAll);

  node4_v4<<<NODE_TILES, 256, 0, stream>>>(x0, WhAll, bq, bk, bv, bsk, Qn, Kn, Vn, Skip);
  edge_attn<<<EA_BLOCKS, 256, 0, stream>>>(ea, elist, srcs, dsts, WhAll + 4 * 16384, be,
                                           Qn, Kn, Vn, attn, den);
  post_ln_div<<<12500, 256, 0, stream>>>(attn, den, Skip, x0, g1, lb1, node1);
  gemm_v4<0, 1><<<NODE_TILES, 256, 0, stream>>>(node1, (long)N_NODES, NODE_TILES,
                                                WhAll + 5 * 16384, b1, hid);
  gemm_v4<0, 0><<<NODE_TILES, 256, 0, stream>>>(hid, (long)N_NODES, NODE_TILES,
                                                WhAll + 6 * 16384, b2, h2);
  post_ln<<<12500, 256, 0, stream>>>(h2, node1, g2, lb2, (float*)d_out);
}

// Round 12
// 618.112 us; speedup vs baseline: 1.4141x; 1.4141x over previous
//
#include <hip/hip_runtime.h>
#include <hip/hip_fp16.h>

#define N_NODES 50000
#define N_EDGES 800000
#define DIM 128
#define NODE_TILES 782   // ceil(50000/64)
#define EDGE_TILES 12500 // 800000/64

typedef _Float16 f16;
typedef _Float16 f16x2 __attribute__((ext_vector_type(2)));
typedef _Float16 f16x4 __attribute__((ext_vector_type(4)));
typedef _Float16 f16x8 __attribute__((ext_vector_type(8)));
typedef float    f32x16 __attribute__((ext_vector_type(16)));

__device__ __forceinline__ void sfence() { __builtin_amdgcn_sched_barrier(0); }

// ---------------- shared GEMM pieces ----------------
__device__ __forceinline__ void load_wfrag(const f16* __restrict__ Wh, int ch, int l31, int g,
                                           f16x8 bf[2][8]) {
#pragma unroll
  for (int c = 0; c < 2; ++c)
#pragma unroll
    for (int ks = 0; ks < 8; ++ks)
      bf[c][ks] = *(const f16x8*)(Wh + ((ch * 64 + c * 32 + l31) << 7) + 16 * ks + 8 * g);
}

template <int HALF_OUT, int SILU>
__device__ __forceinline__ void gemm_store(f32x16 acc[2], long M, const float* __restrict__ Bv,
                                           void* __restrict__ OUT,
                                           long tile0, int rc, int ch, int l31, int g) {
#pragma unroll
  for (int c = 0; c < 2; ++c) {
    int col = ch * 64 + c * 32 + l31;
    float bv = Bv[col];
#pragma unroll
    for (int r = 0; r < 16; ++r) {
      long gm = tile0 + rc * 32 + ((r & 3) + 8 * (r >> 2) + 4 * g);
      if (gm < M) {
        float v = acc[c][r] + bv;
        if (SILU) v = v / (1.0f + __expf(-v));
        if (HALF_OUT) ((f16*)OUT)[gm * DIM + col] = (f16)v;
        else          ((float*)OUT)[gm * DIM + col] = v;
      }
    }
  }
}

// ---------------- staging: coalesced, f32->f16, XOR-swizzled LDS ----------------
__device__ __forceinline__ void stage_issue(const float* __restrict__ X, long M, long base,
                                            int tid, float4 sv[8]) {
#pragma unroll
  for (int kk = 0; kk < 8; ++kk) {
    int i = tid + kk * 256;            // [0, 2048): 64 rows x 32 slots of 16B(f32)
    long row = base + (i >> 5);
    long gr = row < M ? row : (M - 1);
    sv[kk] = *(const float4*)(X + gr * DIM + (i & 31) * 4);   // fully coalesced
  }
}

// gather variant: tile rows are elist[base..base+64) (dst-sorted edge order)
__device__ __forceinline__ void stage_issue_g(const float* __restrict__ X,
                                              const int* __restrict__ elist, long base,
                                              int tid, float4 sv[8]) {
#pragma unroll
  for (int kk = 0; kk < 8; ++kk) {
    int i = tid + kk * 256;
    int eid = elist[base + (i >> 5)];      // L2-hot, broadcast within 32-thread group
    sv[kk] = *(const float4*)(X + (long)eid * DIM + (i & 31) * 4);  // full 512B row segs
  }
}

__device__ __forceinline__ void stage_write(const float4 sv[8], int tid, f16* __restrict__ lds) {
#pragma unroll
  for (int kk = 0; kk < 8; ++kk) {
    int i = tid + kk * 256;
    int r = i >> 5, s8 = i & 31;
    f16x4 h;
    h[0] = (f16)sv[kk].x; h[1] = (f16)sv[kk].y; h[2] = (f16)sv[kk].z; h[3] = (f16)sv[kk].w;
    *(f16x4*)(lds + r * 128 + (((s8 >> 1) ^ (r & 15)) << 3) + ((s8 & 1) << 2)) = h;
  }
}

// gemm over LDS tile
__device__ __forceinline__ void mfma_lds_g(const f16* __restrict__ A, int lr, int g,
                                           const f16x8 bf[2][8], f32x16 acc[2]) {
#pragma unroll
  for (int c = 0; c < 2; ++c)
#pragma unroll
    for (int k = 0; k < 16; ++k) acc[c][k] = 0.0f;
#pragma unroll
  for (int ks = 0; ks < 8; ++ks) {
    f16x8 a = *(const f16x8*)(A + lr * 128 + (((2 * ks + g) ^ (lr & 15)) << 3));
    acc[0] = __builtin_amdgcn_mfma_f32_32x32x16_f16(a, bf[0][ks], acc[0], 0, 0, 0);
    acc[1] = __builtin_amdgcn_mfma_f32_32x32x16_f16(a, bf[1][ks], acc[1], 0, 0, 0);
  }
}

// ---------------- GEMM v4g (rows gathered via elist), double-buffered ----------------
template <int HALF_OUT>
__global__ __launch_bounds__(256) void gemm_v4g(const float* __restrict__ X, long M, int ntiles,
                                                const int* __restrict__ elist,
                                                const f16* __restrict__ Wh,
                                                const float* __restrict__ Bv,
                                                void* __restrict__ OUT) {
  __shared__ f16 lbuf[2][64 * 128];
  int tid = threadIdx.x;
  int lane = tid & 63, w = tid >> 6;
  int rc = w >> 1, ch = w & 1, l31 = lane & 31, g = lane >> 5;
  int t0 = blockIdx.x;
  if (t0 >= ntiles) return;
  f16x8 bf[2][8];
  load_wfrag(Wh, ch, l31, g, bf);
  float4 sv[8];
  stage_issue_g(X, elist, (long)t0 * 64, tid, sv);
  stage_write(sv, tid, lbuf[0]);
  __syncthreads();
  int cur = 0;
  int lr = rc * 32 + l31;
  for (int t = t0; t < ntiles; t += gridDim.x) {
    int tn = t + gridDim.x;
    if (tn < ntiles) stage_issue_g(X, elist, (long)tn * 64, tid, sv);
    sfence();
    f32x16 acc[2];
    mfma_lds_g(lbuf[cur], lr, g, bf, acc);
    gemm_store<HALF_OUT, 0>(acc, M, Bv, OUT, (long)t * 64, rc, ch, l31, g);
    if (tn < ntiles) {
      asm volatile("s_waitcnt vmcnt(0)" ::: "memory");
      stage_write(sv, tid, lbuf[cur ^ 1]);
    }
    __syncthreads();
    cur ^= 1;
  }
}

// ---------------- node4 v4: X-tile staged once, 4 weight mats ----------------
__global__ __launch_bounds__(256) void node4_v4(const float* __restrict__ X,
    const f16* __restrict__ WhAll,
    const float* __restrict__ bq, const float* __restrict__ bk,
    const float* __restrict__ bv_, const float* __restrict__ bs,
    f16* __restrict__ Q, f16* __restrict__ K, f16* __restrict__ V, float* __restrict__ S) {
  __shared__ f16 xs[64 * 128];
  int tid = threadIdx.x;
  int lane = tid & 63, w = tid >> 6;
  int rc = w >> 1, ch = w & 1, l31 = lane & 31, g = lane >> 5;
  int t = blockIdx.x;
  if (t >= NODE_TILES) return;
  long tile0 = (long)t * 64;
  float4 sv[8];
  stage_issue(X, N_NODES, tile0, tid, sv);
  stage_write(sv, tid, xs);
  __syncthreads();
  int lr = rc * 32 + l31;
#pragma unroll 1
  for (int mat = 0; mat < 4; ++mat) {
    f16x8 bf[2][8];
    load_wfrag(WhAll + mat * 16384, ch, l31, g, bf);
    f32x16 acc[2];
    mfma_lds_g(xs, lr, g, bf, acc);
    if (mat == 0)      gemm_store<1, 0>(acc, N_NODES, bq, Q, tile0, rc, ch, l31, g);
    else if (mat == 1) gemm_store<1, 0>(acc, N_NODES, bk, K, tile0, rc, ch, l31, g);
    else if (mat == 2) gemm_store<1, 0>(acc, N_NODES, bv_, V, tile0, rc, ch, l31, g);
    else               gemm_store<0, 0>(acc, N_NODES, bs, S, tile0, rc, ch, l31, g);
  }
}

// ---------------- fused MLP + LN2: hid and h2 never touch HBM ----------------
// Single 32 KB LDS buffer with well-defined aliasing:
//   phase 1: first 16 KB = xs (X tile, f16 swizzled)
//   phase 2: second 16 KB = hs (hid tile, f16 swizzled)   [xs dead after MFMA-1]
//   phase 3: all 32 KB = wbuf (h2 tile, f32)              [xs,hs dead after MFMA-2]
__global__ __launch_bounds__(256) void mlp_ln(const float* __restrict__ X,
    const f16* __restrict__ W1h, const float* __restrict__ b1,
    const f16* __restrict__ W2h, const float* __restrict__ b2,
    const float* __restrict__ gv, const float* __restrict__ bv,
    float* __restrict__ outp) {
  __shared__ float smem[64 * 128];    // 32 KB
  f16* xs = (f16*)smem;               // first 16 KB
  f16* hs = (f16*)smem + 64 * 128;    // second 16 KB
  float* wbuf = smem;                 // full 32 KB
  int tid = threadIdx.x;
  int lane = tid & 63, w = tid >> 6;
  int rc = w >> 1, ch = w & 1, l31 = lane & 31, g = lane >> 5;
  int t = blockIdx.x;
  if (t >= NODE_TILES) return;
  long tile0 = (long)t * 64;
  int lr = rc * 32 + l31;

  float4 sv[8];
  stage_issue(X, N_NODES, tile0, tid, sv);
  f16x8 bf1[2][8];
  load_wfrag(W1h, ch, l31, g, bf1);
  stage_write(sv, tid, xs);
  __syncthreads();

  f32x16 acc[2];
  mfma_lds_g(xs, lr, g, bf1, acc);
  f16x8 bf2[2][8];
  load_wfrag(W2h, ch, l31, g, bf2);

  // hid = silu(acc + b1) -> hs, swizzled for MFMA A-read
#pragma unroll
  for (int c = 0; c < 2; ++c) {
    int col = ch * 64 + c * 32 + l31;
    float bb = b1[col];
#pragma unroll
    for (int r = 0; r < 16; ++r) {
      int row = rc * 32 + (r & 3) + 8 * (r >> 2) + 4 * g;
      float v = acc[c][r] + bb;
      v = v / (1.0f + __expf(-v));
      hs[row * 128 + (((col >> 3) ^ (row & 15)) << 3) + (col & 7)] = (f16)v;
    }
  }
  __syncthreads();

  f32x16 a2[2];
  mfma_lds_g(hs, lr, g, bf2, a2);
  __syncthreads();                    // all hs reads done before wbuf overwrite

#pragma unroll
  for (int c = 0; c < 2; ++c) {
    int col = ch * 64 + c * 32 + l31;
    float bb = b2[col];
#pragma unroll
    for (int r = 0; r < 16; ++r) {
      int row = rc * 32 + (r & 3) + 8 * (r >> 2) + 4 * g;
      wbuf[row * 128 + col] = a2[c][r] + bb;
    }
  }
  __syncthreads();

  // per-row LN: wave w handles rows [w*16, w*16+16)
  float2 gg = *(const float2*)(gv + 2 * lane);
  float2 bb2 = *(const float2*)(bv + 2 * lane);
#pragma unroll 1
  for (int rr = 0; rr < 16; ++rr) {
    int row = w * 16 + rr;
    long gm = tile0 + row;
    if (gm >= N_NODES) break;
    float2 x;
    x.x = wbuf[row * 128 + 2 * lane];
    x.y = wbuf[row * 128 + 2 * lane + 1];
    float sm = x.x + x.y;
    for (int m = 1; m < 64; m <<= 1) sm += __shfl_xor(sm, m);
    float mu = sm * (1.f / 128.f);
    float dx = x.x - mu, dy = x.y - mu;
    float ss = dx * dx + dy * dy;
    for (int m = 1; m < 64; m <<= 1) ss += __shfl_xor(ss, m);
    float r = rsqrtf(ss * (1.f / 128.f) + 1e-5f);
    float2 bs = *(const float2*)(X + gm * DIM + 2 * lane);
    float2 o;
    o.x = bs.x + dx * r * gg.x + bb2.x;
    o.y = bs.y + dy * r * gg.y + bb2.y;
    *(float2*)(outp + gm * DIM + 2 * lane) = o;
  }
}

// convert all 7 weight matrices f32 -> f16
__global__ void convert7(const float* __restrict__ a0, const float* __restrict__ a1,
                         const float* __restrict__ a2, const float* __restrict__ a3,
                         const float* __restrict__ a4, const float* __restrict__ a5,
                         const float* __restrict__ a6, f16* __restrict__ dst) {
  int i = blockIdx.x * blockDim.x + threadIdx.x;
  int mat = i >> 14, el = i & 16383;
  const float* s = (mat == 0) ? a0 : (mat == 1) ? a1 : (mat == 2) ? a2 : (mat == 3) ? a3
                 : (mat == 4) ? a4 : (mat == 5) ? a5 : a6;
  dst[i] = (f16)s[el];
}

// ---------------- CSR build ----------------
__global__ void hist_k(const int* __restrict__ ei, int* __restrict__ counts) {
  for (long e = blockIdx.x * (long)blockDim.x + threadIdx.x; e < N_EDGES;
       e += (long)gridDim.x * blockDim.x)
    atomicAdd(&counts[ei[N_EDGES + e]], 1);
}

__global__ __launch_bounds__(1024) void scan_k(const int* __restrict__ counts,
                                               int* __restrict__ offs, int* __restrict__ cursor) {
  __shared__ int sd[1024];
  int tid = threadIdx.x;
  const int CH = (N_NODES + 1023) / 1024;
  int i0 = tid * CH;
  int s = 0;
  for (int i = 0; i < CH; ++i) { int idx = i0 + i; if (idx < N_NODES) s += counts[idx]; }
  sd[tid] = s; __syncthreads();
  for (int off = 1; off < 1024; off <<= 1) {
    int v = (tid >= off) ? sd[tid - off] : 0;
    __syncthreads();
    sd[tid] += v;
    __syncthreads();
  }
  int run = sd[tid] - s;
  for (int i = 0; i < CH; ++i) {
    int idx = i0 + i;
    if (idx < N_NODES) { offs[idx] = run; cursor[idx] = run; run += counts[idx]; }
  }
  if (tid == 1023) offs[N_NODES] = run;
}

// scatter: elist[pos]=edge id; srcs[pos]=src node of that edge
__global__ void scatter_k(const int* __restrict__ ei, int* __restrict__ cursor,
                          int* __restrict__ elist, int* __restrict__ srcs) {
  for (long e = blockIdx.x * (long)blockDim.x + threadIdx.x; e < N_EDGES;
       e += (long)gridDim.x * blockDim.x) {
    int d = ei[N_EDGES + e];
    int pos = atomicAdd(&cursor[d], 1);
    elist[pos] = (int)e;
    srcs[pos] = ei[e];
  }
}

// ---------------- fused attention + softmax + LN1 ----------------
// per dst node (1 wave): single pass over dst-sorted emat/srcs (sequential),
// K/V gathers (L3-hot); then softmax-div + Skip + LN inline; write node1.
__global__ __launch_bounds__(256) void attn_ln(const int* __restrict__ offs,
    const int* __restrict__ srcs, const f16* __restrict__ emat, const f16* __restrict__ Qn,
    const f16* __restrict__ Kn, const f16* __restrict__ Vn,
    const float* __restrict__ Skip, const float* __restrict__ base,
    const float* __restrict__ gv, const float* __restrict__ bv,
    float* __restrict__ outp) {
  int n = blockIdx.x * 4 + (threadIdx.x >> 6);
  if (n >= N_NODES) return;
  int lane = threadIdx.x & 63;
  float qx, qy;
  { f16x2 q2 = *(const f16x2*)(Qn + (long)n * DIM + 2 * lane); qx = (float)q2[0]; qy = (float)q2[1]; }
  int rs = offs[n], re = offs[n + 1];
  float a0 = 0.f, a1 = 0.f, den = 0.f;
  int s_n = (rs < re) ? srcs[rs] : 0;
  for (int i = rs; i < re; ++i) {
    int s = s_n;
    if (i + 1 < re) s_n = srcs[i + 1];
    f16x2 e2 = *(const f16x2*)(emat + (long)i * DIM + 2 * lane);
    f16x2 k2 = *(const f16x2*)(Kn + (long)s * DIM + 2 * lane);
    f16x2 v2 = *(const f16x2*)(Vn + (long)s * DIM + 2 * lane);
    float p = qx * ((float)k2[0] + (float)e2[0]) + qy * ((float)k2[1] + (float)e2[1]);
    p += __shfl_xor(p, 1);
    p += __shfl_xor(p, 2);
    p += __shfl_xor(p, 4);
    float ex = __expf(p * 0.25f);
    den += ex;
    a0 += ex * ((float)e2[0] + (float)v2[0]);
    a1 += ex * ((float)e2[1] + (float)v2[1]);
  }
  float inv = 1.f / (den + 1e-16f);
  float2 sk = *(const float2*)(Skip + (long)n * DIM + 2 * lane);
  float2 x;
  x.x = a0 * inv + sk.x;
  x.y = a1 * inv + sk.y;
  float sm = x.x + x.y;
  for (int m = 1; m < 64; m <<= 1) sm += __shfl_xor(sm, m);
  float mu = sm * (1.f / 128.f);
  float dx = x.x - mu, dy = x.y - mu;
  float ss = dx * dx + dy * dy;
  for (int m = 1; m < 64; m <<= 1) ss += __shfl_xor(ss, m);
  float r = rsqrtf(ss * (1.f / 128.f) + 1e-5f);
  float2 gg = *(const float2*)(gv + 2 * lane);
  float2 bb = *(const float2*)(bv + 2 * lane);
  float2 bs = *(const float2*)(base + (long)n * DIM + 2 * lane);
  float2 o;
  o.x = bs.x + dx * r * gg.x + bb.x;
  o.y = bs.y + dy * r * gg.y + bb.y;
  *(float2*)(outp + (long)n * DIM + 2 * lane) = o;
}

// ---------------- launch ----------------
extern "C" void kernel_launch(void* const* d_in, const int* in_sizes, int n_in,
                              void* d_out, int out_size, void* d_ws, size_t ws_size,
                              hipStream_t stream) {
  (void)in_sizes; (void)n_in; (void)out_size; (void)ws_size;
  const int*   ei  = (const int*)d_in[0];
  const float* x0  = (const float*)d_in[1];
  const float* ea  = (const float*)d_in[2];
  const float* Wq  = (const float*)d_in[3];  const float* bq = (const float*)d_in[4];
  const float* Wk  = (const float*)d_in[5];  const float* bk = (const float*)d_in[6];
  const float* Wv  = (const float*)d_in[7];  const float* bv = (const float*)d_in[8];
  const float* We  = (const float*)d_in[9];  const float* be = (const float*)d_in[10];
  const float* Wsk = (const float*)d_in[11]; const float* bsk = (const float*)d_in[12];
  const float* W1  = (const float*)d_in[13]; const float* b1 = (const float*)d_in[14];
  const float* W2  = (const float*)d_in[15]; const float* b2 = (const float*)d_in[16];
  const float* g1  = (const float*)d_in[17]; const float* lb1 = (const float*)d_in[18];
  const float* g2  = (const float*)d_in[19]; const float* lb2 = (const float*)d_in[20];

  char* ws = (char*)d_ws;
  f16*   Qn     = (f16*)(ws + 0);              // 12.8M
  f16*   Kn     = (f16*)(ws + 12800000L);      // 12.8M
  f16*   Vn     = (f16*)(ws + 25600000L);      // 12.8M
  float* Skip   = (float*)(ws + 38400000L);    // 25.6M -> 64,000,000
  int*   offs   = (int*)(ws + 64000000L);      // 200,192
  f16*   WhAll  = (f16*)(ws + 64200192L);      // 229,376 (overlays cursor, dead after CSR)
  int*   cursor = (int*)(ws + 64200192L);
  int*   counts = (int*)(ws + 64429568L);      // 200,000
  int*   elist  = (int*)(ws + 64629760L);      // 3.2M
  int*   srcs   = (int*)(ws + 67829760L);      // 3.2M
  f16*   emat   = (f16*)(ws + 71029760L);      // 204.8M (dst-sorted) -> 275,829,760
  float* node1  = (float*)(ws + 275829760L);   // 25.6M -> 301,429,760

  (void)hipMemsetAsync(counts, 0, N_NODES * sizeof(int), stream);
  hist_k<<<1024, 256, 0, stream>>>(ei, counts);
  scan_k<<<1, 1024, 0, stream>>>(counts, offs, cursor);
  scatter_k<<<1024, 256, 0, stream>>>(ei, cursor, elist, srcs);
  convert7<<<112, 1024, 0, stream>>>(Wq, Wk, Wv, Wsk, We, W1, W2, WhAll);

  node4_v4<<<NODE_TILES, 256, 0, stream>>>(x0, WhAll, bq, bk, bv, bsk, Qn, Kn, Vn, Skip);
  gemm_v4g<1><<<2500, 256, 0, stream>>>(ea, (long)N_EDGES, EDGE_TILES, elist,
                                        WhAll + 4 * 16384, be, emat);
  attn_ln<<<12500, 256, 0, stream>>>(offs, srcs, emat, Qn, Kn, Vn, Skip, x0, g1, lb1, node1);
  mlp_ln<<<NODE_TILES, 256, 0, stream>>>(node1, WhAll + 5 * 16384, b1,
                                         WhAll + 6 * 16384, b2, g2, lb2, (float*)d_out);
}

// Round 13
// 502.517 us; speedup vs baseline: 1.7394x; 1.2300x over previous
//
#include <hip/hip_runtime.h>
#include <hip/hip_fp16.h>

#define N_NODES 50000
#define N_EDGES 800000
#define DIM 128
#define NODE_TILES 782   // ceil(50000/64)
#define EDGE_TILES 12500 // 800000/64
#define SCAN_NB 50       // 50 blocks x 1000 counts

typedef _Float16 f16;
typedef _Float16 f16x2 __attribute__((ext_vector_type(2)));
typedef _Float16 f16x4 __attribute__((ext_vector_type(4)));
typedef _Float16 f16x8 __attribute__((ext_vector_type(8)));
typedef float    f32x16 __attribute__((ext_vector_type(16)));

__device__ __forceinline__ void sfence() { __builtin_amdgcn_sched_barrier(0); }

// ---------------- shared GEMM pieces ----------------
__device__ __forceinline__ void load_wfrag(const f16* __restrict__ Wh, int ch, int l31, int g,
                                           f16x8 bf[2][8]) {
#pragma unroll
  for (int c = 0; c < 2; ++c)
#pragma unroll
    for (int ks = 0; ks < 8; ++ks)
      bf[c][ks] = *(const f16x8*)(Wh + ((ch * 64 + c * 32 + l31) << 7) + 16 * ks + 8 * g);
}

template <int HALF_OUT, int SILU>
__device__ __forceinline__ void gemm_store(f32x16 acc[2], long M, const float* __restrict__ Bv,
                                           void* __restrict__ OUT,
                                           long tile0, int rc, int ch, int l31, int g) {
#pragma unroll
  for (int c = 0; c < 2; ++c) {
    int col = ch * 64 + c * 32 + l31;
    float bv = Bv[col];
#pragma unroll
    for (int r = 0; r < 16; ++r) {
      long gm = tile0 + rc * 32 + ((r & 3) + 8 * (r >> 2) + 4 * g);
      if (gm < M) {
        float v = acc[c][r] + bv;
        if (SILU) v = v / (1.0f + __expf(-v));
        if (HALF_OUT) ((f16*)OUT)[gm * DIM + col] = (f16)v;
        else          ((float*)OUT)[gm * DIM + col] = v;
      }
    }
  }
}

// ---------------- staging: coalesced, f32->f16, XOR-swizzled LDS ----------------
__device__ __forceinline__ void stage_issue(const float* __restrict__ X, long M, long base,
                                            int tid, float4 sv[8]) {
#pragma unroll
  for (int kk = 0; kk < 8; ++kk) {
    int i = tid + kk * 256;
    long row = base + (i >> 5);
    long gr = row < M ? row : (M - 1);
    sv[kk] = *(const float4*)(X + gr * DIM + (i & 31) * 4);
  }
}

__device__ __forceinline__ void stage_issue_g(const float* __restrict__ X,
                                              const int* __restrict__ elist, long base,
                                              int tid, float4 sv[8]) {
#pragma unroll
  for (int kk = 0; kk < 8; ++kk) {
    int i = tid + kk * 256;
    int eid = elist[base + (i >> 5)];
    sv[kk] = *(const float4*)(X + (long)eid * DIM + (i & 31) * 4);
  }
}

__device__ __forceinline__ void stage_write(const float4 sv[8], int tid, f16* __restrict__ lds) {
#pragma unroll
  for (int kk = 0; kk < 8; ++kk) {
    int i = tid + kk * 256;
    int r = i >> 5, s8 = i & 31;
    f16x4 h;
    h[0] = (f16)sv[kk].x; h[1] = (f16)sv[kk].y; h[2] = (f16)sv[kk].z; h[3] = (f16)sv[kk].w;
    *(f16x4*)(lds + r * 128 + (((s8 >> 1) ^ (r & 15)) << 3) + ((s8 & 1) << 2)) = h;
  }
}

__device__ __forceinline__ void mfma_lds_g(const f16* __restrict__ A, int lr, int g,
                                           const f16x8 bf[2][8], f32x16 acc[2]) {
#pragma unroll
  for (int c = 0; c < 2; ++c)
#pragma unroll
    for (int k = 0; k < 16; ++k) acc[c][k] = 0.0f;
#pragma unroll
  for (int ks = 0; ks < 8; ++ks) {
    f16x8 a = *(const f16x8*)(A + lr * 128 + (((2 * ks + g) ^ (lr & 15)) << 3));
    acc[0] = __builtin_amdgcn_mfma_f32_32x32x16_f16(a, bf[0][ks], acc[0], 0, 0, 0);
    acc[1] = __builtin_amdgcn_mfma_f32_32x32x16_f16(a, bf[1][ks], acc[1], 0, 0, 0);
  }
}

// ---------------- GEMM v4g (rows gathered via elist), double-buffered ----------------
template <int HALF_OUT>
__global__ __launch_bounds__(256) void gemm_v4g(const float* __restrict__ X, long M, int ntiles,
                                                const int* __restrict__ elist,
                                                const f16* __restrict__ Wh,
                                                const float* __restrict__ Bv,
                                                void* __restrict__ OUT) {
  __shared__ f16 lbuf[2][64 * 128];
  int tid = threadIdx.x;
  int lane = tid & 63, w = tid >> 6;
  int rc = w >> 1, ch = w & 1, l31 = lane & 31, g = lane >> 5;
  int t0 = blockIdx.x;
  if (t0 >= ntiles) return;
  f16x8 bf[2][8];
  load_wfrag(Wh, ch, l31, g, bf);
  float4 sv[8];
  stage_issue_g(X, elist, (long)t0 * 64, tid, sv);
  stage_write(sv, tid, lbuf[0]);
  __syncthreads();
  int cur = 0;
  int lr = rc * 32 + l31;
  for (int t = t0; t < ntiles; t += gridDim.x) {
    int tn = t + gridDim.x;
    if (tn < ntiles) stage_issue_g(X, elist, (long)tn * 64, tid, sv);
    sfence();
    f32x16 acc[2];
    mfma_lds_g(lbuf[cur], lr, g, bf, acc);
    gemm_store<HALF_OUT, 0>(acc, M, Bv, OUT, (long)t * 64, rc, ch, l31, g);
    if (tn < ntiles) {
      asm volatile("s_waitcnt vmcnt(0)" ::: "memory");
      stage_write(sv, tid, lbuf[cur ^ 1]);
    }
    __syncthreads();
    cur ^= 1;
  }
}

// ---------------- node4 v4: X-tile staged once, 4 weight mats ----------------
__global__ __launch_bounds__(256) void node4_v4(const float* __restrict__ X,
    const f16* __restrict__ WhAll,
    const float* __restrict__ bq, const float* __restrict__ bk,
    const float* __restrict__ bv_, const float* __restrict__ bs,
    f16* __restrict__ Q, f16* __restrict__ K, f16* __restrict__ V, float* __restrict__ S) {
  __shared__ f16 xs[64 * 128];
  int tid = threadIdx.x;
  int lane = tid & 63, w = tid >> 6;
  int rc = w >> 1, ch = w & 1, l31 = lane & 31, g = lane >> 5;
  int t = blockIdx.x;
  if (t >= NODE_TILES) return;
  long tile0 = (long)t * 64;
  float4 sv[8];
  stage_issue(X, N_NODES, tile0, tid, sv);
  stage_write(sv, tid, xs);
  __syncthreads();
  int lr = rc * 32 + l31;
#pragma unroll 1
  for (int mat = 0; mat < 4; ++mat) {
    f16x8 bf[2][8];
    load_wfrag(WhAll + mat * 16384, ch, l31, g, bf);
    f32x16 acc[2];
    mfma_lds_g(xs, lr, g, bf, acc);
    if (mat == 0)      gemm_store<1, 0>(acc, N_NODES, bq, Q, tile0, rc, ch, l31, g);
    else if (mat == 1) gemm_store<1, 0>(acc, N_NODES, bk, K, tile0, rc, ch, l31, g);
    else if (mat == 2) gemm_store<1, 0>(acc, N_NODES, bv_, V, tile0, rc, ch, l31, g);
    else               gemm_store<0, 0>(acc, N_NODES, bs, S, tile0, rc, ch, l31, g);
  }
}

// ---------------- fused MLP + LN2 (single 32 KB LDS, phase-aliased) ----------------
__global__ __launch_bounds__(256) void mlp_ln(const float* __restrict__ X,
    const f16* __restrict__ W1h, const float* __restrict__ b1,
    const f16* __restrict__ W2h, const float* __restrict__ b2,
    const float* __restrict__ gv, const float* __restrict__ bv,
    float* __restrict__ outp) {
  __shared__ float smem[64 * 128];    // 32 KB
  f16* xs = (f16*)smem;               // first 16 KB
  f16* hs = (f16*)smem + 64 * 128;    // second 16 KB
  float* wbuf = smem;                 // full 32 KB
  int tid = threadIdx.x;
  int lane = tid & 63, w = tid >> 6;
  int rc = w >> 1, ch = w & 1, l31 = lane & 31, g = lane >> 5;
  int t = blockIdx.x;
  if (t >= NODE_TILES) return;
  long tile0 = (long)t * 64;
  int lr = rc * 32 + l31;

  float4 sv[8];
  stage_issue(X, N_NODES, tile0, tid, sv);
  f16x8 bf1[2][8];
  load_wfrag(W1h, ch, l31, g, bf1);
  stage_write(sv, tid, xs);
  __syncthreads();

  f32x16 acc[2];
  mfma_lds_g(xs, lr, g, bf1, acc);
  f16x8 bf2[2][8];
  load_wfrag(W2h, ch, l31, g, bf2);

#pragma unroll
  for (int c = 0; c < 2; ++c) {
    int col = ch * 64 + c * 32 + l31;
    float bb = b1[col];
#pragma unroll
    for (int r = 0; r < 16; ++r) {
      int row = rc * 32 + (r & 3) + 8 * (r >> 2) + 4 * g;
      float v = acc[c][r] + bb;
      v = v / (1.0f + __expf(-v));
      hs[row * 128 + (((col >> 3) ^ (row & 15)) << 3) + (col & 7)] = (f16)v;
    }
  }
  __syncthreads();

  f32x16 a2[2];
  mfma_lds_g(hs, lr, g, bf2, a2);
  __syncthreads();

#pragma unroll
  for (int c = 0; c < 2; ++c) {
    int col = ch * 64 + c * 32 + l31;
    float bb = b2[col];
#pragma unroll
    for (int r = 0; r < 16; ++r) {
      int row = rc * 32 + (r & 3) + 8 * (r >> 2) + 4 * g;
      wbuf[row * 128 + col] = a2[c][r] + bb;
    }
  }
  __syncthreads();

  float2 gg = *(const float2*)(gv + 2 * lane);
  float2 bb2 = *(const float2*)(bv + 2 * lane);
#pragma unroll 1
  for (int rr = 0; rr < 16; ++rr) {
    int row = w * 16 + rr;
    long gm = tile0 + row;
    if (gm >= N_NODES) break;
    float2 x;
    x.x = wbuf[row * 128 + 2 * lane];
    x.y = wbuf[row * 128 + 2 * lane + 1];
    float sm = x.x + x.y;
    for (int m = 1; m < 64; m <<= 1) sm += __shfl_xor(sm, m);
    float mu = sm * (1.f / 128.f);
    float dx = x.x - mu, dy = x.y - mu;
    float ss = dx * dx + dy * dy;
    for (int m = 1; m < 64; m <<= 1) ss += __shfl_xor(ss, m);
    float r = rsqrtf(ss * (1.f / 128.f) + 1e-5f);
    float2 bs = *(const float2*)(X + gm * DIM + 2 * lane);
    float2 o;
    o.x = bs.x + dx * r * gg.x + bb2.x;
    o.y = bs.y + dy * r * gg.y + bb2.y;
    *(float2*)(outp + gm * DIM + 2 * lane) = o;
  }
}

// convert all 7 weight matrices f32 -> f16
__global__ void convert7(const float* __restrict__ a0, const float* __restrict__ a1,
                         const float* __restrict__ a2, const float* __restrict__ a3,
                         const float* __restrict__ a4, const float* __restrict__ a5,
                         const float* __restrict__ a6, f16* __restrict__ dst) {
  int i = blockIdx.x * blockDim.x + threadIdx.x;
  int mat = i >> 14, el = i & 16383;
  const float* s = (mat == 0) ? a0 : (mat == 1) ? a1 : (mat == 2) ? a2 : (mat == 3) ? a3
                 : (mat == 4) ? a4 : (mat == 5) ? a5 : a6;
  dst[i] = (f16)s[el];
}

// ---------------- CSR build (parallel scan) ----------------
__global__ void hist_k(const int* __restrict__ ei, int* __restrict__ counts) {
  for (long e = blockIdx.x * (long)blockDim.x + threadIdx.x; e < N_EDGES;
       e += (long)gridDim.x * blockDim.x)
    atomicAdd(&counts[ei[N_EDGES + e]], 1);
}

// phase A: per-block sums of 1000 counts
__global__ __launch_bounds__(1024) void blocksum_k(const int* __restrict__ counts,
                                                   int* __restrict__ bsum) {
  __shared__ int sd[1024];
  int t = threadIdx.x, b = blockIdx.x;
  int v = (t < 1000) ? counts[b * 1000 + t] : 0;
  sd[t] = v; __syncthreads();
  for (int off = 512; off > 0; off >>= 1) {
    if (t < off) sd[t] += sd[t + off];
    __syncthreads();
  }
  if (t == 0) bsum[b] = sd[0];
}

// phase B: serial exclusive scan of 50 block sums (tiny)
__global__ void scan_small(const int* __restrict__ bsum, int* __restrict__ boff,
                           int* __restrict__ offs) {
  if (threadIdx.x == 0) {
    int run = 0;
    for (int b = 0; b < SCAN_NB; ++b) { boff[b] = run; run += bsum[b]; }
    boff[SCAN_NB] = run;
    offs[N_NODES] = run;
  }
}

// phase C: in-block exclusive scan + add block offset; write offs & cursor
__global__ __launch_bounds__(1024) void expand_k(const int* __restrict__ counts,
                                                 const int* __restrict__ boff,
                                                 int* __restrict__ offs, int* __restrict__ cursor) {
  __shared__ int sd[1024];
  int t = threadIdx.x, b = blockIdx.x;
  int v = (t < 1000) ? counts[b * 1000 + t] : 0;
  sd[t] = v; __syncthreads();
  for (int off = 1; off < 1024; off <<= 1) {
    int x = (t >= off) ? sd[t - off] : 0;
    __syncthreads();
    sd[t] += x;
    __syncthreads();
  }
  if (t < 1000) {
    int o = boff[b] + sd[t] - v;     // exclusive prefix
    int idx = b * 1000 + t;
    offs[idx] = o;
    cursor[idx] = o;
  }
}

// scatter: elist[pos]=edge id; srcs[pos]=src node of that edge
__global__ void scatter_k(const int* __restrict__ ei, int* __restrict__ cursor,
                          int* __restrict__ elist, int* __restrict__ srcs) {
  for (long e = blockIdx.x * (long)blockDim.x + threadIdx.x; e < N_EDGES;
       e += (long)gridDim.x * blockDim.x) {
    int d = ei[N_EDGES + e];
    int pos = atomicAdd(&cursor[d], 1);
    elist[pos] = (int)e;
    srcs[pos] = ei[e];
  }
}

// ---------------- fused attention + softmax + LN1, 2 edges/iteration ----------------
// per dst node (1 wave): lane l covers cols 4*(l&31)..+3; half=l>>5 takes edges i, i+1.
// emat/srcs sequential; K/V gathers L2/L3-hot. Softmax-div + Skip + LN inline.
__global__ __launch_bounds__(256) void attn_ln(const int* __restrict__ offs,
    const int* __restrict__ srcs, const f16* __restrict__ emat, const f16* __restrict__ Qn,
    const f16* __restrict__ Kn, const f16* __restrict__ Vn,
    const float* __restrict__ Skip, const float* __restrict__ base,
    const float* __restrict__ gv, const float* __restrict__ bv,
    float* __restrict__ outp) {
  int n = blockIdx.x * 4 + (threadIdx.x >> 6);
  if (n >= N_NODES) return;
  int lane = threadIdx.x & 63;
  int half = lane >> 5, li = lane & 31;
  int c4 = 4 * li;

  float q0, q1, q2, q3;
  { f16x4 q = *(const f16x4*)(Qn + (long)n * DIM + c4);
    q0 = (float)q[0]; q1 = (float)q[1]; q2 = (float)q[2]; q3 = (float)q[3]; }

  int rs = offs[n], re = offs[n + 1];
  float a0 = 0.f, a1 = 0.f, a2 = 0.f, a3 = 0.f, den = 0.f;
  if (rs < re) {
    int e0 = rs + half;
    int sCur = srcs[(e0 < re) ? e0 : (re - 1)];
    for (int i = rs; i < re; i += 2) {
      int ei_ = i + half;
      bool valid = ei_ < re;
      int ec = valid ? ei_ : (re - 1);
      int s = sCur;
      int en = ei_ + 2;
      sCur = srcs[(en < re) ? en : (re - 1)];
      f16x4 e4 = *(const f16x4*)(emat + (long)ec * DIM + c4);
      f16x4 k4 = *(const f16x4*)(Kn + (long)s * DIM + c4);
      f16x4 v4 = *(const f16x4*)(Vn + (long)s * DIM + c4);
      float p = q0 * ((float)k4[0] + (float)e4[0]) + q1 * ((float)k4[1] + (float)e4[1])
              + q2 * ((float)k4[2] + (float)e4[2]) + q3 * ((float)k4[3] + (float)e4[3]);
      p += __shfl_xor(p, 1);
      p += __shfl_xor(p, 2);              // 4-lane group == one head (16 cols)
      float ex = valid ? __expf(p * 0.25f) : 0.f;
      den += ex;
      a0 += ex * ((float)e4[0] + (float)v4[0]);
      a1 += ex * ((float)e4[1] + (float)v4[1]);
      a2 += ex * ((float)e4[2] + (float)v4[2]);
      a3 += ex * ((float)e4[3] + (float)v4[3]);
    }
  }
  // combine the two edge-halves (cols identical across halves)
  a0 += __shfl_xor(a0, 32); a1 += __shfl_xor(a1, 32);
  a2 += __shfl_xor(a2, 32); a3 += __shfl_xor(a3, 32);
  den += __shfl_xor(den, 32);

  float inv = 1.f / (den + 1e-16f);
  float4 sk = *(const float4*)(Skip + (long)n * DIM + c4);
  float x0v = a0 * inv + sk.x, x1v = a1 * inv + sk.y;
  float x2v = a2 * inv + sk.z, x3v = a3 * inv + sk.w;

  float sm = x0v + x1v + x2v + x3v;
  for (int m = 1; m < 32; m <<= 1) sm += __shfl_xor(sm, m);
  float mu = sm * (1.f / 128.f);
  float d0 = x0v - mu, d1 = x1v - mu, d2 = x2v - mu, d3 = x3v - mu;
  float ss = d0 * d0 + d1 * d1 + d2 * d2 + d3 * d3;
  for (int m = 1; m < 32; m <<= 1) ss += __shfl_xor(ss, m);
  float r = rsqrtf(ss * (1.f / 128.f) + 1e-5f);

  if (half == 0) {
    float4 gg = *(const float4*)(gv + c4);
    float4 bb = *(const float4*)(bv + c4);
    float4 bs = *(const float4*)(base + (long)n * DIM + c4);
    float4 o;
    o.x = bs.x + d0 * r * gg.x + bb.x;
    o.y = bs.y + d1 * r * gg.y + bb.y;
    o.z = bs.z + d2 * r * gg.z + bb.z;
    o.w = bs.w + d3 * r * gg.w + bb.w;
    *(float4*)(outp + (long)n * DIM + c4) = o;
  }
}

// ---------------- launch ----------------
extern "C" void kernel_launch(void* const* d_in, const int* in_sizes, int n_in,
                              void* d_out, int out_size, void* d_ws, size_t ws_size,
                              hipStream_t stream) {
  (void)in_sizes; (void)n_in; (void)out_size; (void)ws_size;
  const int*   ei  = (const int*)d_in[0];
  const float* x0  = (const float*)d_in[1];
  const float* ea  = (const float*)d_in[2];
  const float* Wq  = (const float*)d_in[3];  const float* bq = (const float*)d_in[4];
  const float* Wk  = (const float*)d_in[5];  const float* bk = (const float*)d_in[6];
  const float* Wv  = (const float*)d_in[7];  const float* bv = (const float*)d_in[8];
  const float* We  = (const float*)d_in[9];  const float* be = (const float*)d_in[10];
  const float* Wsk = (const float*)d_in[11]; const float* bsk = (const float*)d_in[12];
  const float* W1  = (const float*)d_in[13]; const float* b1 = (const float*)d_in[14];
  const float* W2  = (const float*)d_in[15]; const float* b2 = (const float*)d_in[16];
  const float* g1  = (const float*)d_in[17]; const float* lb1 = (const float*)d_in[18];
  const float* g2  = (const float*)d_in[19]; const float* lb2 = (const float*)d_in[20];

  char* ws = (char*)d_ws;
  f16*   Qn     = (f16*)(ws + 0);              // 12.8M
  f16*   Kn     = (f16*)(ws + 12800000L);      // 12.8M
  f16*   Vn     = (f16*)(ws + 25600000L);      // 12.8M
  float* Skip   = (float*)(ws + 38400000L);    // 25.6M -> 64,000,000
  int*   offs   = (int*)(ws + 64000000L);      // 200,192
  f16*   WhAll  = (f16*)(ws + 64200192L);      // 229,376 (overlays cursor, dead after CSR)
  int*   cursor = (int*)(ws + 64200192L);
  int*   counts = (int*)(ws + 64429568L);      // 200,000
  int*   bsum   = (int*)(ws + 64629760L);      // 512 B (bsum[50] + boff[51])
  int*   boff   = bsum + 64;
  int*   elist  = (int*)(ws + 64630272L);      // 3.2M
  int*   srcs   = (int*)(ws + 67830272L);      // 3.2M
  f16*   emat   = (f16*)(ws + 71030272L);      // 204.8M (dst-sorted) -> 275,830,272
  float* node1  = (float*)(ws + 275830272L);   // 25.6M -> 301,430,272

  (void)hipMemsetAsync(counts, 0, N_NODES * sizeof(int), stream);
  hist_k<<<1024, 256, 0, stream>>>(ei, counts);
  blocksum_k<<<SCAN_NB, 1024, 0, stream>>>(counts, bsum);
  scan_small<<<1, 64, 0, stream>>>(bsum, boff, offs);
  expand_k<<<SCAN_NB, 1024, 0, stream>>>(counts, boff, offs, cursor);
  scatter_k<<<1024, 256, 0, stream>>>(ei, cursor, elist, srcs);
  convert7<<<112, 1024, 0, stream>>>(Wq, Wk, Wv, Wsk, We, W1, W2, WhAll);

  node4_v4<<<NODE_TILES, 256, 0, stream>>>(x0, WhAll, bq, bk, bv, bsk, Qn, Kn, Vn, Skip);
  gemm_v4g<1><<<2500, 256, 0, stream>>>(ea, (long)N_EDGES, EDGE_TILES, elist,
                                        WhAll + 4 * 16384, be, emat);
  attn_ln<<<12500, 256, 0, stream>>>(offs, srcs, emat, Qn, Kn, Vn, Skip, x0, g1, lb1, node1);
  mlp_ln<<<NODE_TILES, 256, 0, stream>>>(node1, WhAll + 5 * 16384, b1,
                                         WhAll + 6 * 16384, b2, g2, lb2, (float*)d_out);
}

// Round 14
// 490.076 us; speedup vs baseline: 1.7836x; 1.0254x over previous
//
#include <hip/hip_runtime.h>
#include <hip/hip_fp16.h>

#define N_NODES 50000
#define N_EDGES 800000
#define DIM 128
#define NODE_TILES 782   // ceil(50000/64)
#define EDGE_TILES 12500 // 800000/64
#define SCAN_NB 50       // 50 blocks x 1000 counts

typedef _Float16 f16;
typedef _Float16 f16x2 __attribute__((ext_vector_type(2)));
typedef _Float16 f16x4 __attribute__((ext_vector_type(4)));
typedef _Float16 f16x8 __attribute__((ext_vector_type(8)));
typedef float    f32x16 __attribute__((ext_vector_type(16)));

__device__ __forceinline__ void sfence() { __builtin_amdgcn_sched_barrier(0); }

// ---------------- shared GEMM pieces ----------------
__device__ __forceinline__ void load_wfrag(const f16* __restrict__ Wh, int ch, int l31, int g,
                                           f16x8 bf[2][8]) {
#pragma unroll
  for (int c = 0; c < 2; ++c)
#pragma unroll
    for (int ks = 0; ks < 8; ++ks)
      bf[c][ks] = *(const f16x8*)(Wh + ((ch * 64 + c * 32 + l31) << 7) + 16 * ks + 8 * g);
}

template <int HALF_OUT, int SILU>
__device__ __forceinline__ void gemm_store(f32x16 acc[2], long M, const float* __restrict__ Bv,
                                           void* __restrict__ OUT,
                                           long tile0, int rc, int ch, int l31, int g) {
#pragma unroll
  for (int c = 0; c < 2; ++c) {
    int col = ch * 64 + c * 32 + l31;
    float bv = Bv[col];
#pragma unroll
    for (int r = 0; r < 16; ++r) {
      long gm = tile0 + rc * 32 + ((r & 3) + 8 * (r >> 2) + 4 * g);
      if (gm < M) {
        float v = acc[c][r] + bv;
        if (SILU) v = v / (1.0f + __expf(-v));
        if (HALF_OUT) ((f16*)OUT)[gm * DIM + col] = (f16)v;
        else          ((float*)OUT)[gm * DIM + col] = v;
      }
    }
  }
}

// ---------------- staging: coalesced, f32->f16, XOR-swizzled LDS ----------------
__device__ __forceinline__ void stage_issue(const float* __restrict__ X, long M, long base,
                                            int tid, float4 sv[8]) {
#pragma unroll
  for (int kk = 0; kk < 8; ++kk) {
    int i = tid + kk * 256;
    long row = base + (i >> 5);
    long gr = row < M ? row : (M - 1);
    sv[kk] = *(const float4*)(X + gr * DIM + (i & 31) * 4);
  }
}

__device__ __forceinline__ void stage_issue_g(const float* __restrict__ X,
                                              const int* __restrict__ elist, long base,
                                              int tid, float4 sv[8]) {
#pragma unroll
  for (int kk = 0; kk < 8; ++kk) {
    int i = tid + kk * 256;
    int eid = elist[base + (i >> 5)];
    sv[kk] = *(const float4*)(X + (long)eid * DIM + (i & 31) * 4);
  }
}

__device__ __forceinline__ void stage_write(const float4 sv[8], int tid, f16* __restrict__ lds) {
#pragma unroll
  for (int kk = 0; kk < 8; ++kk) {
    int i = tid + kk * 256;
    int r = i >> 5, s8 = i & 31;
    f16x4 h;
    h[0] = (f16)sv[kk].x; h[1] = (f16)sv[kk].y; h[2] = (f16)sv[kk].z; h[3] = (f16)sv[kk].w;
    *(f16x4*)(lds + r * 128 + (((s8 >> 1) ^ (r & 15)) << 3) + ((s8 & 1) << 2)) = h;
  }
}

__device__ __forceinline__ void mfma_lds_g(const f16* __restrict__ A, int lr, int g,
                                           const f16x8 bf[2][8], f32x16 acc[2]) {
#pragma unroll
  for (int c = 0; c < 2; ++c)
#pragma unroll
    for (int k = 0; k < 16; ++k) acc[c][k] = 0.0f;
#pragma unroll
  for (int ks = 0; ks < 8; ++ks) {
    f16x8 a = *(const f16x8*)(A + lr * 128 + (((2 * ks + g) ^ (lr & 15)) << 3));
    acc[0] = __builtin_amdgcn_mfma_f32_32x32x16_f16(a, bf[0][ks], acc[0], 0, 0, 0);
    acc[1] = __builtin_amdgcn_mfma_f32_32x32x16_f16(a, bf[1][ks], acc[1], 0, 0, 0);
  }
}

// ---------------- GEMM v4g (rows gathered via elist), double-buffered ----------------
template <int HALF_OUT>
__global__ __launch_bounds__(256) void gemm_v4g(const float* __restrict__ X, long M, int ntiles,
                                                const int* __restrict__ elist,
                                                const f16* __restrict__ Wh,
                                                const float* __restrict__ Bv,
                                                void* __restrict__ OUT) {
  __shared__ f16 lbuf[2][64 * 128];
  int tid = threadIdx.x;
  int lane = tid & 63, w = tid >> 6;
  int rc = w >> 1, ch = w & 1, l31 = lane & 31, g = lane >> 5;
  int t0 = blockIdx.x;
  if (t0 >= ntiles) return;
  f16x8 bf[2][8];
  load_wfrag(Wh, ch, l31, g, bf);
  float4 sv[8];
  stage_issue_g(X, elist, (long)t0 * 64, tid, sv);
  stage_write(sv, tid, lbuf[0]);
  __syncthreads();
  int cur = 0;
  int lr = rc * 32 + l31;
  for (int t = t0; t < ntiles; t += gridDim.x) {
    int tn = t + gridDim.x;
    if (tn < ntiles) stage_issue_g(X, elist, (long)tn * 64, tid, sv);
    sfence();
    f32x16 acc[2];
    mfma_lds_g(lbuf[cur], lr, g, bf, acc);
    gemm_store<HALF_OUT, 0>(acc, M, Bv, OUT, (long)t * 64, rc, ch, l31, g);
    if (tn < ntiles) {
      asm volatile("s_waitcnt vmcnt(0)" ::: "memory");
      stage_write(sv, tid, lbuf[cur ^ 1]);
    }
    __syncthreads();
    cur ^= 1;
  }
}

// ---------------- node4 v4: X-tile staged once, 4 weight mats ----------------
__global__ __launch_bounds__(256) void node4_v4(const float* __restrict__ X,
    const f16* __restrict__ WhAll,
    const float* __restrict__ bq, const float* __restrict__ bk,
    const float* __restrict__ bv_, const float* __restrict__ bs,
    f16* __restrict__ Q, f16* __restrict__ K, f16* __restrict__ V, float* __restrict__ S) {
  __shared__ f16 xs[64 * 128];
  int tid = threadIdx.x;
  int lane = tid & 63, w = tid >> 6;
  int rc = w >> 1, ch = w & 1, l31 = lane & 31, g = lane >> 5;
  int t = blockIdx.x;
  if (t >= NODE_TILES) return;
  long tile0 = (long)t * 64;
  float4 sv[8];
  stage_issue(X, N_NODES, tile0, tid, sv);
  stage_write(sv, tid, xs);
  __syncthreads();
  int lr = rc * 32 + l31;
#pragma unroll 1
  for (int mat = 0; mat < 4; ++mat) {
    f16x8 bf[2][8];
    load_wfrag(WhAll + mat * 16384, ch, l31, g, bf);
    f32x16 acc[2];
    mfma_lds_g(xs, lr, g, bf, acc);
    if (mat == 0)      gemm_store<1, 0>(acc, N_NODES, bq, Q, tile0, rc, ch, l31, g);
    else if (mat == 1) gemm_store<1, 0>(acc, N_NODES, bk, K, tile0, rc, ch, l31, g);
    else if (mat == 2) gemm_store<1, 0>(acc, N_NODES, bv_, V, tile0, rc, ch, l31, g);
    else               gemm_store<0, 0>(acc, N_NODES, bs, S, tile0, rc, ch, l31, g);
  }
}

// ---------------- fused MLP + LN2 (single 32 KB LDS, phase-aliased) ----------------
__global__ __launch_bounds__(256) void mlp_ln(const float* __restrict__ X,
    const f16* __restrict__ W1h, const float* __restrict__ b1,
    const f16* __restrict__ W2h, const float* __restrict__ b2,
    const float* __restrict__ gv, const float* __restrict__ bv,
    float* __restrict__ outp) {
  __shared__ float smem[64 * 128];    // 32 KB
  f16* xs = (f16*)smem;               // first 16 KB
  f16* hs = (f16*)smem + 64 * 128;    // second 16 KB
  float* wbuf = smem;                 // full 32 KB
  int tid = threadIdx.x;
  int lane = tid & 63, w = tid >> 6;
  int rc = w >> 1, ch = w & 1, l31 = lane & 31, g = lane >> 5;
  int t = blockIdx.x;
  if (t >= NODE_TILES) return;
  long tile0 = (long)t * 64;
  int lr = rc * 32 + l31;

  float4 sv[8];
  stage_issue(X, N_NODES, tile0, tid, sv);
  f16x8 bf1[2][8];
  load_wfrag(W1h, ch, l31, g, bf1);
  stage_write(sv, tid, xs);
  __syncthreads();

  f32x16 acc[2];
  mfma_lds_g(xs, lr, g, bf1, acc);
  f16x8 bf2[2][8];
  load_wfrag(W2h, ch, l31, g, bf2);

#pragma unroll
  for (int c = 0; c < 2; ++c) {
    int col = ch * 64 + c * 32 + l31;
    float bb = b1[col];
#pragma unroll
    for (int r = 0; r < 16; ++r) {
      int row = rc * 32 + (r & 3) + 8 * (r >> 2) + 4 * g;
      float v = acc[c][r] + bb;
      v = v / (1.0f + __expf(-v));
      hs[row * 128 + (((col >> 3) ^ (row & 15)) << 3) + (col & 7)] = (f16)v;
    }
  }
  __syncthreads();

  f32x16 a2[2];
  mfma_lds_g(hs, lr, g, bf2, a2);
  __syncthreads();

#pragma unroll
  for (int c = 0; c < 2; ++c) {
    int col = ch * 64 + c * 32 + l31;
    float bb = b2[col];
#pragma unroll
    for (int r = 0; r < 16; ++r) {
      int row = rc * 32 + (r & 3) + 8 * (r >> 2) + 4 * g;
      wbuf[row * 128 + col] = a2[c][r] + bb;
    }
  }
  __syncthreads();

  float2 gg = *(const float2*)(gv + 2 * lane);
  float2 bb2 = *(const float2*)(bv + 2 * lane);
#pragma unroll 1
  for (int rr = 0; rr < 16; ++rr) {
    int row = w * 16 + rr;
    long gm = tile0 + row;
    if (gm >= N_NODES) break;
    float2 x;
    x.x = wbuf[row * 128 + 2 * lane];
    x.y = wbuf[row * 128 + 2 * lane + 1];
    float sm = x.x + x.y;
    for (int m = 1; m < 64; m <<= 1) sm += __shfl_xor(sm, m);
    float mu = sm * (1.f / 128.f);
    float dx = x.x - mu, dy = x.y - mu;
    float ss = dx * dx + dy * dy;
    for (int m = 1; m < 64; m <<= 1) ss += __shfl_xor(ss, m);
    float r = rsqrtf(ss * (1.f / 128.f) + 1e-5f);
    float2 bs = *(const float2*)(X + gm * DIM + 2 * lane);
    float2 o;
    o.x = bs.x + dx * r * gg.x + bb2.x;
    o.y = bs.y + dy * r * gg.y + bb2.y;
    *(float2*)(outp + gm * DIM + 2 * lane) = o;
  }
}

// convert all 7 weight matrices f32 -> f16
__global__ void convert7(const float* __restrict__ a0, const float* __restrict__ a1,
                         const float* __restrict__ a2, const float* __restrict__ a3,
                         const float* __restrict__ a4, const float* __restrict__ a5,
                         const float* __restrict__ a6, f16* __restrict__ dst) {
  int i = blockIdx.x * blockDim.x + threadIdx.x;
  int mat = i >> 14, el = i & 16383;
  const float* s = (mat == 0) ? a0 : (mat == 1) ? a1 : (mat == 2) ? a2 : (mat == 3) ? a3
                 : (mat == 4) ? a4 : (mat == 5) ? a5 : a6;
  dst[i] = (f16)s[el];
}

// ---------------- CSR build (parallel scan) ----------------
__global__ void hist_k(const int* __restrict__ ei, int* __restrict__ counts) {
  for (long e = blockIdx.x * (long)blockDim.x + threadIdx.x; e < N_EDGES;
       e += (long)gridDim.x * blockDim.x)
    atomicAdd(&counts[ei[N_EDGES + e]], 1);
}

__global__ __launch_bounds__(1024) void blocksum_k(const int* __restrict__ counts,
                                                   int* __restrict__ bsum) {
  __shared__ int sd[1024];
  int t = threadIdx.x, b = blockIdx.x;
  int v = (t < 1000) ? counts[b * 1000 + t] : 0;
  sd[t] = v; __syncthreads();
  for (int off = 512; off > 0; off >>= 1) {
    if (t < off) sd[t] += sd[t + off];
    __syncthreads();
  }
  if (t == 0) bsum[b] = sd[0];
}

__global__ void scan_small(const int* __restrict__ bsum, int* __restrict__ boff,
                           int* __restrict__ offs) {
  if (threadIdx.x == 0) {
    int run = 0;
    for (int b = 0; b < SCAN_NB; ++b) { boff[b] = run; run += bsum[b]; }
    boff[SCAN_NB] = run;
    offs[N_NODES] = run;
  }
}

__global__ __launch_bounds__(1024) void expand_k(const int* __restrict__ counts,
                                                 const int* __restrict__ boff,
                                                 int* __restrict__ offs, int* __restrict__ cursor) {
  __shared__ int sd[1024];
  int t = threadIdx.x, b = blockIdx.x;
  int v = (t < 1000) ? counts[b * 1000 + t] : 0;
  sd[t] = v; __syncthreads();
  for (int off = 1; off < 1024; off <<= 1) {
    int x = (t >= off) ? sd[t - off] : 0;
    __syncthreads();
    sd[t] += x;
    __syncthreads();
  }
  if (t < 1000) {
    int o = boff[b] + sd[t] - v;
    int idx = b * 1000 + t;
    offs[idx] = o;
    cursor[idx] = o;
  }
}

__global__ void scatter_k(const int* __restrict__ ei, int* __restrict__ cursor,
                          int* __restrict__ elist, int* __restrict__ srcs) {
  for (long e = blockIdx.x * (long)blockDim.x + threadIdx.x; e < N_EDGES;
       e += (long)gridDim.x * blockDim.x) {
    int d = ei[N_EDGES + e];
    int pos = atomicAdd(&cursor[d], 1);
    elist[pos] = (int)e;
    srcs[pos] = ei[e];
  }
}

// ---------------- fused attention + softmax + LN1, 4 edges/iteration ----------------
// per dst node (1 wave): 4 groups of 16 lanes; group j takes edge i+j; lane covers
// 8 cols via one f16x8 load per table. Head (16 cols) = lane pair -> 1 shfl reduce.
// Group partials combined with shfl_xor(16,32). Softmax-div + Skip + LN inline.
__global__ __launch_bounds__(256) void attn_ln(const int* __restrict__ offs,
    const int* __restrict__ srcs, const f16* __restrict__ emat, const f16* __restrict__ Qn,
    const f16* __restrict__ Kn, const f16* __restrict__ Vn,
    const float* __restrict__ Skip, const float* __restrict__ base,
    const float* __restrict__ gv, const float* __restrict__ bv,
    float* __restrict__ outp) {
  int n = blockIdx.x * 4 + (threadIdx.x >> 6);
  if (n >= N_NODES) return;
  int lane = threadIdx.x & 63;
  int grp = lane >> 4, li = lane & 15;
  int c8 = 8 * li;                     // 8-col slice owned by this lane

  float q[8];
  {
    f16x8 qv = *(const f16x8*)(Qn + (long)n * DIM + c8);
#pragma unroll
    for (int k = 0; k < 8; ++k) q[k] = (float)qv[k];
  }

  int rs = offs[n], re = offs[n + 1];
  float a[8];
#pragma unroll
  for (int k = 0; k < 8; ++k) a[k] = 0.f;
  float den = 0.f;

  if (rs < re) {
    int e0 = rs + grp;
    int sCur = srcs[(e0 < re) ? e0 : (re - 1)];
    for (int i = rs; i < re; i += 4) {
      int ei_ = i + grp;
      bool valid = ei_ < re;
      int ec = valid ? ei_ : (re - 1);
      int s = sCur;
      int en = ei_ + 4;
      sCur = srcs[(en < re) ? en : (re - 1)];
      f16x8 e8 = *(const f16x8*)(emat + (long)ec * DIM + c8);
      f16x8 k8 = *(const f16x8*)(Kn + (long)s * DIM + c8);
      f16x8 v8 = *(const f16x8*)(Vn + (long)s * DIM + c8);
      float p = 0.f;
#pragma unroll
      for (int k = 0; k < 8; ++k) p += q[k] * ((float)k8[k] + (float)e8[k]);
      p += __shfl_xor(p, 1);           // lane pair = one head (16 cols)
      float ex = valid ? __expf(p * 0.25f) : 0.f;
      den += ex;
#pragma unroll
      for (int k = 0; k < 8; ++k) a[k] += ex * ((float)e8[k] + (float)v8[k]);
    }
  }
  // combine the 4 edge-groups (same cols in every group)
#pragma unroll
  for (int k = 0; k < 8; ++k) {
    a[k] += __shfl_xor(a[k], 16);
    a[k] += __shfl_xor(a[k], 32);
  }
  den += __shfl_xor(den, 16);
  den += __shfl_xor(den, 32);

  float inv = 1.f / (den + 1e-16f);
  float x[8];
  {
    float4 sk0 = *(const float4*)(Skip + (long)n * DIM + c8);
    float4 sk1 = *(const float4*)(Skip + (long)n * DIM + c8 + 4);
    x[0] = a[0] * inv + sk0.x; x[1] = a[1] * inv + sk0.y;
    x[2] = a[2] * inv + sk0.z; x[3] = a[3] * inv + sk0.w;
    x[4] = a[4] * inv + sk1.x; x[5] = a[5] * inv + sk1.y;
    x[6] = a[6] * inv + sk1.z; x[7] = a[7] * inv + sk1.w;
  }

  float sm = 0.f;
#pragma unroll
  for (int k = 0; k < 8; ++k) sm += x[k];
  for (int m = 1; m < 16; m <<= 1) sm += __shfl_xor(sm, m);
  float mu = sm * (1.f / 128.f);
  float d[8], ss = 0.f;
#pragma unroll
  for (int k = 0; k < 8; ++k) { d[k] = x[k] - mu; ss += d[k] * d[k]; }
  for (int m = 1; m < 16; m <<= 1) ss += __shfl_xor(ss, m);
  float r = rsqrtf(ss * (1.f / 128.f) + 1e-5f);

  if (grp == 0) {
    float4 g0 = *(const float4*)(gv + c8);
    float4 g1 = *(const float4*)(gv + c8 + 4);
    float4 b0 = *(const float4*)(bv + c8);
    float4 b1 = *(const float4*)(bv + c8 + 4);
    float4 s0 = *(const float4*)(base + (long)n * DIM + c8);
    float4 s1 = *(const float4*)(base + (long)n * DIM + c8 + 4);
    float4 o0, o1;
    o0.x = s0.x + d[0] * r * g0.x + b0.x;
    o0.y = s0.y + d[1] * r * g0.y + b0.y;
    o0.z = s0.z + d[2] * r * g0.z + b0.z;
    o0.w = s0.w + d[3] * r * g0.w + b0.w;
    o1.x = s1.x + d[4] * r * g1.x + b1.x;
    o1.y = s1.y + d[5] * r * g1.y + b1.y;
    o1.z = s1.z + d[6] * r * g1.z + b1.z;
    o1.w = s1.w + d[7] * r * g1.w + b1.w;
    *(float4*)(outp + (long)n * DIM + c8) = o0;
    *(float4*)(outp + (long)n * DIM + c8 + 4) = o1;
  }
}

// ---------------- launch ----------------
extern "C" void kernel_launch(void* const* d_in, const int* in_sizes, int n_in,
                              void* d_out, int out_size, void* d_ws, size_t ws_size,
                              hipStream_t stream) {
  (void)in_sizes; (void)n_in; (void)out_size; (void)ws_size;
  const int*   ei  = (const int*)d_in[0];
  const float* x0  = (const float*)d_in[1];
  const float* ea  = (const float*)d_in[2];
  const float* Wq  = (const float*)d_in[3];  const float* bq = (const float*)d_in[4];
  const float* Wk  = (const float*)d_in[5];  const float* bk = (const float*)d_in[6];
  const float* Wv  = (const float*)d_in[7];  const float* bv = (const float*)d_in[8];
  const float* We  = (const float*)d_in[9];  const float* be = (const float*)d_in[10];
  const float* Wsk = (const float*)d_in[11]; const float* bsk = (const float*)d_in[12];
  const float* W1  = (const float*)d_in[13]; const float* b1 = (const float*)d_in[14];
  const float* W2  = (const float*)d_in[15]; const float* b2 = (const float*)d_in[16];
  const float* g1  = (const float*)d_in[17]; const float* lb1 = (const float*)d_in[18];
  const float* g2  = (const float*)d_in[19]; const float* lb2 = (const float*)d_in[20];

  char* ws = (char*)d_ws;
  f16*   Qn     = (f16*)(ws + 0);              // 12.8M
  f16*   Kn     = (f16*)(ws + 12800000L);      // 12.8M
  f16*   Vn     = (f16*)(ws + 25600000L);      // 12.8M
  float* Skip   = (float*)(ws + 38400000L);    // 25.6M -> 64,000,000
  int*   offs   = (int*)(ws + 64000000L);      // 200,192
  f16*   WhAll  = (f16*)(ws + 64200192L);      // 229,376 (overlays cursor, dead after CSR)
  int*   cursor = (int*)(ws + 64200192L);
  int*   counts = (int*)(ws + 64429568L);      // 200,000
  int*   bsum   = (int*)(ws + 64629760L);      // 512 B (bsum[50] + boff[51])
  int*   boff   = bsum + 64;
  int*   elist  = (int*)(ws + 64630272L);      // 3.2M
  int*   srcs   = (int*)(ws + 67830272L);      // 3.2M
  f16*   emat   = (f16*)(ws + 71030272L);      // 204.8M (dst-sorted)
  float* node1  = (float*)(ws + 275830272L);   // 25.6M

  (void)hipMemsetAsync(counts, 0, N_NODES * sizeof(int), stream);
  hist_k<<<1024, 256, 0, stream>>>(ei, counts);
  blocksum_k<<<SCAN_NB, 1024, 0, stream>>>(counts, bsum);
  scan_small<<<1, 64, 0, stream>>>(bsum, boff, offs);
  expand_k<<<SCAN_NB, 1024, 0, stream>>>(counts, boff, offs, cursor);
  scatter_k<<<1024, 256, 0, stream>>>(ei, cursor, elist, srcs);
  convert7<<<112, 1024, 0, stream>>>(Wq, Wk, Wv, Wsk, We, W1, W2, WhAll);

  node4_v4<<<NODE_TILES, 256, 0, stream>>>(x0, WhAll, bq, bk, bv, bsk, Qn, Kn, Vn, Skip);
  gemm_v4g<1><<<2500, 256, 0, stream>>>(ea, (long)N_EDGES, EDGE_TILES, elist,
                                        WhAll + 4 * 16384, be, emat);
  attn_ln<<<12500, 256, 0, stream>>>(offs, srcs, emat, Qn, Kn, Vn, Skip, x0, g1, lb1, node1);
  mlp_ln<<<NODE_TILES, 256, 0, stream>>>(node1, WhAll + 5 * 16384, b1,
                                         WhAll + 6 * 16384, b2, g2, lb2, (float*)d_out);
}

// Round 15
// 471.759 us; speedup vs baseline: 1.8528x; 1.0388x over previous
//
#include <hip/hip_runtime.h>
#include <hip/hip_fp16.h>

#define N_NODES 50000
#define N_EDGES 800000
#define DIM 128
#define NODE_TILES 782   // ceil(50000/64)
#define EDGE_TILES 12500 // 800000/64
#define EDGE_BLOCKS 2500
#define SCAN_NB 50       // 50 blocks x 1000 counts

typedef _Float16 f16;
typedef _Float16 f16x2 __attribute__((ext_vector_type(2)));
typedef _Float16 f16x4 __attribute__((ext_vector_type(4)));
typedef _Float16 f16x8 __attribute__((ext_vector_type(8)));
typedef float    f32x16 __attribute__((ext_vector_type(16)));

__device__ __forceinline__ void sfence() { __builtin_amdgcn_sched_barrier(0); }

// ---------------- shared GEMM pieces ----------------
__device__ __forceinline__ void load_wfrag(const f16* __restrict__ Wh, int ch, int l31, int g,
                                           f16x8 bf[2][8]) {
#pragma unroll
  for (int c = 0; c < 2; ++c)
#pragma unroll
    for (int ks = 0; ks < 8; ++ks)
      bf[c][ks] = *(const f16x8*)(Wh + ((ch * 64 + c * 32 + l31) << 7) + 16 * ks + 8 * g);
}

template <int HALF_OUT, int SILU>
__device__ __forceinline__ void gemm_store(f32x16 acc[2], long M, const float* __restrict__ Bv,
                                           void* __restrict__ OUT,
                                           long tile0, int rc, int ch, int l31, int g) {
#pragma unroll
  for (int c = 0; c < 2; ++c) {
    int col = ch * 64 + c * 32 + l31;
    float bv = Bv[col];
#pragma unroll
    for (int r = 0; r < 16; ++r) {
      long gm = tile0 + rc * 32 + ((r & 3) + 8 * (r >> 2) + 4 * g);
      if (gm < M) {
        float v = acc[c][r] + bv;
        if (SILU) v = v / (1.0f + __expf(-v));
        if (HALF_OUT) ((f16*)OUT)[gm * DIM + col] = (f16)v;
        else          ((float*)OUT)[gm * DIM + col] = v;
      }
    }
  }
}

// ---------------- staging: coalesced, f32->f16, XOR-swizzled LDS ----------------
__device__ __forceinline__ void stage_issue(const float* __restrict__ X, long M, long base,
                                            int tid, float4 sv[8]) {
#pragma unroll
  for (int kk = 0; kk < 8; ++kk) {
    int i = tid + kk * 256;
    long row = base + (i >> 5);
    long gr = row < M ? row : (M - 1);
    sv[kk] = *(const float4*)(X + gr * DIM + (i & 31) * 4);
  }
}

__device__ __forceinline__ void stage_issue_g(const float* __restrict__ X,
                                              const int* __restrict__ elist, long base,
                                              int tid, float4 sv[8]) {
#pragma unroll
  for (int kk = 0; kk < 8; ++kk) {
    int i = tid + kk * 256;
    int eid = elist[base + (i >> 5)];
    sv[kk] = *(const float4*)(X + (long)eid * DIM + (i & 31) * 4);
  }
}

__device__ __forceinline__ void stage_write(const float4 sv[8], int tid, f16* __restrict__ lds) {
#pragma unroll
  for (int kk = 0; kk < 8; ++kk) {
    int i = tid + kk * 256;
    int r = i >> 5, s8 = i & 31;
    f16x4 h;
    h[0] = (f16)sv[kk].x; h[1] = (f16)sv[kk].y; h[2] = (f16)sv[kk].z; h[3] = (f16)sv[kk].w;
    *(f16x4*)(lds + r * 128 + (((s8 >> 1) ^ (r & 15)) << 3) + ((s8 & 1) << 2)) = h;
  }
}

__device__ __forceinline__ void mfma_lds_g(const f16* __restrict__ A, int lr, int g,
                                           const f16x8 bf[2][8], f32x16 acc[2]) {
#pragma unroll
  for (int c = 0; c < 2; ++c)
#pragma unroll
    for (int k = 0; k < 16; ++k) acc[c][k] = 0.0f;
#pragma unroll
  for (int ks = 0; ks < 8; ++ks) {
    f16x8 a = *(const f16x8*)(A + lr * 128 + (((2 * ks + g) ^ (lr & 15)) << 3));
    acc[0] = __builtin_amdgcn_mfma_f32_32x32x16_f16(a, bf[0][ks], acc[0], 0, 0, 0);
    acc[1] = __builtin_amdgcn_mfma_f32_32x32x16_f16(a, bf[1][ks], acc[1], 0, 0, 0);
  }
}

// ---------------- fused big GEMMs: node4 (blocks 0..781) + edge (blocks 782..3281) ----
__global__ __launch_bounds__(256) void big_gemms(const float* __restrict__ X,
    const float* __restrict__ EA, const int* __restrict__ elist,
    const f16* __restrict__ WhAll,
    const float* __restrict__ bq, const float* __restrict__ bk,
    const float* __restrict__ bv_, const float* __restrict__ bs, const float* __restrict__ be,
    f16* __restrict__ Q, f16* __restrict__ K, f16* __restrict__ V, float* __restrict__ S,
    f16* __restrict__ emat) {
  __shared__ f16 lbuf[2][64 * 128];   // 32 KB both paths
  int tid = threadIdx.x;
  int lane = tid & 63, w = tid >> 6;
  int rc = w >> 1, ch = w & 1, l31 = lane & 31, g = lane >> 5;
  int lr = rc * 32 + l31;

  if (blockIdx.x < NODE_TILES) {
    // ---- node4 path: X-tile staged once, 4 weight mats ----
    f16* xs = lbuf[0];
    long tile0 = (long)blockIdx.x * 64;
    float4 sv[8];
    stage_issue(X, N_NODES, tile0, tid, sv);
    stage_write(sv, tid, xs);
    __syncthreads();
#pragma unroll 1
    for (int mat = 0; mat < 4; ++mat) {
      f16x8 bf[2][8];
      load_wfrag(WhAll + mat * 16384, ch, l31, g, bf);
      f32x16 acc[2];
      mfma_lds_g(xs, lr, g, bf, acc);
      if (mat == 0)      gemm_store<1, 0>(acc, N_NODES, bq, Q, tile0, rc, ch, l31, g);
      else if (mat == 1) gemm_store<1, 0>(acc, N_NODES, bk, K, tile0, rc, ch, l31, g);
      else if (mat == 2) gemm_store<1, 0>(acc, N_NODES, bv_, V, tile0, rc, ch, l31, g);
      else               gemm_store<0, 0>(acc, N_NODES, bs, S, tile0, rc, ch, l31, g);
    }
    return;
  }

  // ---- edge path: gathered-row GEMM, double-buffered, persistent over EDGE_TILES ----
  int t0 = blockIdx.x - NODE_TILES;
  f16x8 bf[2][8];
  load_wfrag(WhAll + 4 * 16384, ch, l31, g, bf);
  float4 sv[8];
  stage_issue_g(EA, elist, (long)t0 * 64, tid, sv);
  stage_write(sv, tid, lbuf[0]);
  __syncthreads();
  int cur = 0;
  for (int t = t0; t < EDGE_TILES; t += EDGE_BLOCKS) {
    int tn = t + EDGE_BLOCKS;
    if (tn < EDGE_TILES) stage_issue_g(EA, elist, (long)tn * 64, tid, sv);
    sfence();
    f32x16 acc[2];
    mfma_lds_g(lbuf[cur], lr, g, bf, acc);
    gemm_store<1, 0>(acc, (long)N_EDGES, be, emat, (long)t * 64, rc, ch, l31, g);
    if (tn < EDGE_TILES) {
      asm volatile("s_waitcnt vmcnt(0)" ::: "memory");
      stage_write(sv, tid, lbuf[cur ^ 1]);
    }
    __syncthreads();
    cur ^= 1;
  }
}

// ---------------- fused MLP + LN2 (single 32 KB LDS, phase-aliased) ----------------
__global__ __launch_bounds__(256) void mlp_ln(const float* __restrict__ X,
    const f16* __restrict__ W1h, const float* __restrict__ b1,
    const f16* __restrict__ W2h, const float* __restrict__ b2,
    const float* __restrict__ gv, const float* __restrict__ bv,
    float* __restrict__ outp) {
  __shared__ float smem[64 * 128];    // 32 KB
  f16* xs = (f16*)smem;               // first 16 KB
  f16* hs = (f16*)smem + 64 * 128;    // second 16 KB
  float* wbuf = smem;                 // full 32 KB
  int tid = threadIdx.x;
  int lane = tid & 63, w = tid >> 6;
  int rc = w >> 1, ch = w & 1, l31 = lane & 31, g = lane >> 5;
  int t = blockIdx.x;
  if (t >= NODE_TILES) return;
  long tile0 = (long)t * 64;
  int lr = rc * 32 + l31;

  float4 sv[8];
  stage_issue(X, N_NODES, tile0, tid, sv);
  f16x8 bf1[2][8];
  load_wfrag(W1h, ch, l31, g, bf1);
  stage_write(sv, tid, xs);
  __syncthreads();

  f32x16 acc[2];
  mfma_lds_g(xs, lr, g, bf1, acc);
  f16x8 bf2[2][8];
  load_wfrag(W2h, ch, l31, g, bf2);

#pragma unroll
  for (int c = 0; c < 2; ++c) {
    int col = ch * 64 + c * 32 + l31;
    float bb = b1[col];
#pragma unroll
    for (int r = 0; r < 16; ++r) {
      int row = rc * 32 + (r & 3) + 8 * (r >> 2) + 4 * g;
      float v = acc[c][r] + bb;
      v = v / (1.0f + __expf(-v));
      hs[row * 128 + (((col >> 3) ^ (row & 15)) << 3) + (col & 7)] = (f16)v;
    }
  }
  __syncthreads();

  f32x16 a2[2];
  mfma_lds_g(hs, lr, g, bf2, a2);
  __syncthreads();

#pragma unroll
  for (int c = 0; c < 2; ++c) {
    int col = ch * 64 + c * 32 + l31;
    float bb = b2[col];
#pragma unroll
    for (int r = 0; r < 16; ++r) {
      int row = rc * 32 + (r & 3) + 8 * (r >> 2) + 4 * g;
      wbuf[row * 128 + col] = a2[c][r] + bb;
    }
  }
  __syncthreads();

  float2 gg = *(const float2*)(gv + 2 * lane);
  float2 bb2 = *(const float2*)(bv + 2 * lane);
#pragma unroll 1
  for (int rr = 0; rr < 16; ++rr) {
    int row = w * 16 + rr;
    long gm = tile0 + row;
    if (gm >= N_NODES) break;
    float2 x;
    x.x = wbuf[row * 128 + 2 * lane];
    x.y = wbuf[row * 128 + 2 * lane + 1];
    float sm = x.x + x.y;
    for (int m = 1; m < 64; m <<= 1) sm += __shfl_xor(sm, m);
    float mu = sm * (1.f / 128.f);
    float dx = x.x - mu, dy = x.y - mu;
    float ss = dx * dx + dy * dy;
    for (int m = 1; m < 64; m <<= 1) ss += __shfl_xor(ss, m);
    float r = rsqrtf(ss * (1.f / 128.f) + 1e-5f);
    float2 bs = *(const float2*)(X + gm * DIM + 2 * lane);
    float2 o;
    o.x = bs.x + dx * r * gg.x + bb2.x;
    o.y = bs.y + dy * r * gg.y + bb2.y;
    *(float2*)(outp + gm * DIM + 2 * lane) = o;
  }
}

// ---------------- CSR build (parallel scan) + weight convert fused into hist ----------
__global__ void hist_conv_k(const int* __restrict__ ei, int* __restrict__ counts,
                            const float* __restrict__ a0, const float* __restrict__ a1,
                            const float* __restrict__ a2, const float* __restrict__ a3,
                            const float* __restrict__ a4, const float* __restrict__ a5,
                            const float* __restrict__ a6, f16* __restrict__ dst) {
  long gid = blockIdx.x * 256L + threadIdx.x;    // grid 1024 x 256 = 262144
  if (gid < 7 * 16384) {
    int mat = (int)(gid >> 14), el = (int)(gid & 16383);
    const float* s = (mat == 0) ? a0 : (mat == 1) ? a1 : (mat == 2) ? a2 : (mat == 3) ? a3
                   : (mat == 4) ? a4 : (mat == 5) ? a5 : a6;
    dst[gid] = (f16)s[el];
  }
  for (long e = gid; e < N_EDGES; e += 1024L * 256)
    atomicAdd(&counts[ei[N_EDGES + e]], 1);
}

__global__ __launch_bounds__(1024) void blocksum_k(const int* __restrict__ counts,
                                                   int* __restrict__ bsum) {
  __shared__ int sd[1024];
  int t = threadIdx.x, b = blockIdx.x;
  int v = (t < 1000) ? counts[b * 1000 + t] : 0;
  sd[t] = v; __syncthreads();
  for (int off = 512; off > 0; off >>= 1) {
    if (t < off) sd[t] += sd[t + off];
    __syncthreads();
  }
  if (t == 0) bsum[b] = sd[0];
}

__global__ void scan_small(const int* __restrict__ bsum, int* __restrict__ boff,
                           int* __restrict__ offs) {
  if (threadIdx.x == 0) {
    int run = 0;
    for (int b = 0; b < SCAN_NB; ++b) { boff[b] = run; run += bsum[b]; }
    boff[SCAN_NB] = run;
    offs[N_NODES] = run;
  }
}

__global__ __launch_bounds__(1024) void expand_k(const int* __restrict__ counts,
                                                 const int* __restrict__ boff,
                                                 int* __restrict__ offs, int* __restrict__ cursor) {
  __shared__ int sd[1024];
  int t = threadIdx.x, b = blockIdx.x;
  int v = (t < 1000) ? counts[b * 1000 + t] : 0;
  sd[t] = v; __syncthreads();
  for (int off = 1; off < 1024; off <<= 1) {
    int x = (t >= off) ? sd[t - off] : 0;
    __syncthreads();
    sd[t] += x;
    __syncthreads();
  }
  if (t < 1000) {
    int o = boff[b] + sd[t] - v;
    int idx = b * 1000 + t;
    offs[idx] = o;
    cursor[idx] = o;
  }
}

__global__ void scatter_k(const int* __restrict__ ei, int* __restrict__ cursor,
                          int* __restrict__ elist, int* __restrict__ srcs) {
  for (long e = blockIdx.x * (long)blockDim.x + threadIdx.x; e < N_EDGES;
       e += (long)gridDim.x * blockDim.x) {
    int d = ei[N_EDGES + e];
    int pos = atomicAdd(&cursor[d], 1);
    elist[pos] = (int)e;
    srcs[pos] = ei[e];
  }
}

// ---------------- fused attention + softmax + LN1, 4 edges/iteration ----------------
__global__ __launch_bounds__(256) void attn_ln(const int* __restrict__ offs,
    const int* __restrict__ srcs, const f16* __restrict__ emat, const f16* __restrict__ Qn,
    const f16* __restrict__ Kn, const f16* __restrict__ Vn,
    const float* __restrict__ Skip, const float* __restrict__ base,
    const float* __restrict__ gv, const float* __restrict__ bv,
    float* __restrict__ outp) {
  int n = blockIdx.x * 4 + (threadIdx.x >> 6);
  if (n >= N_NODES) return;
  int lane = threadIdx.x & 63;
  int grp = lane >> 4, li = lane & 15;
  int c8 = 8 * li;

  float q[8];
  {
    f16x8 qv = *(const f16x8*)(Qn + (long)n * DIM + c8);
#pragma unroll
    for (int k = 0; k < 8; ++k) q[k] = (float)qv[k];
  }

  int rs = offs[n], re = offs[n + 1];
  float a[8];
#pragma unroll
  for (int k = 0; k < 8; ++k) a[k] = 0.f;
  float den = 0.f;

  if (rs < re) {
    int e0 = rs + grp;
    int sCur = srcs[(e0 < re) ? e0 : (re - 1)];
    for (int i = rs; i < re; i += 4) {
      int ei_ = i + grp;
      bool valid = ei_ < re;
      int ec = valid ? ei_ : (re - 1);
      int s = sCur;
      int en = ei_ + 4;
      sCur = srcs[(en < re) ? en : (re - 1)];
      f16x8 e8 = *(const f16x8*)(emat + (long)ec * DIM + c8);
      f16x8 k8 = *(const f16x8*)(Kn + (long)s * DIM + c8);
      f16x8 v8 = *(const f16x8*)(Vn + (long)s * DIM + c8);
      float p = 0.f;
#pragma unroll
      for (int k = 0; k < 8; ++k) p += q[k] * ((float)k8[k] + (float)e8[k]);
      p += __shfl_xor(p, 1);
      float ex = valid ? __expf(p * 0.25f) : 0.f;
      den += ex;
#pragma unroll
      for (int k = 0; k < 8; ++k) a[k] += ex * ((float)e8[k] + (float)v8[k]);
    }
  }
#pragma unroll
  for (int k = 0; k < 8; ++k) {
    a[k] += __shfl_xor(a[k], 16);
    a[k] += __shfl_xor(a[k], 32);
  }
  den += __shfl_xor(den, 16);
  den += __shfl_xor(den, 32);

  float inv = 1.f / (den + 1e-16f);
  float x[8];
  {
    float4 sk0 = *(const float4*)(Skip + (long)n * DIM + c8);
    float4 sk1 = *(const float4*)(Skip + (long)n * DIM + c8 + 4);
    x[0] = a[0] * inv + sk0.x; x[1] = a[1] * inv + sk0.y;
    x[2] = a[2] * inv + sk0.z; x[3] = a[3] * inv + sk0.w;
    x[4] = a[4] * inv + sk1.x; x[5] = a[5] * inv + sk1.y;
    x[6] = a[6] * inv + sk1.z; x[7] = a[7] * inv + sk1.w;
  }

  float sm = 0.f;
#pragma unroll
  for (int k = 0; k < 8; ++k) sm += x[k];
  for (int m = 1; m < 16; m <<= 1) sm += __shfl_xor(sm, m);
  float mu = sm * (1.f / 128.f);
  float d[8], ss = 0.f;
#pragma unroll
  for (int k = 0; k < 8; ++k) { d[k] = x[k] - mu; ss += d[k] * d[k]; }
  for (int m = 1; m < 16; m <<= 1) ss += __shfl_xor(ss, m);
  float r = rsqrtf(ss * (1.f / 128.f) + 1e-5f);

  if (grp == 0) {
    float4 g0 = *(const float4*)(gv + c8);
    float4 g1 = *(const float4*)(gv + c8 + 4);
    float4 b0 = *(const float4*)(bv + c8);
    float4 b1 = *(const float4*)(bv + c8 + 4);
    float4 s0 = *(const float4*)(base + (long)n * DIM + c8);
    float4 s1 = *(const float4*)(base + (long)n * DIM + c8 + 4);
    float4 o0, o1;
    o0.x = s0.x + d[0] * r * g0.x + b0.x;
    o0.y = s0.y + d[1] * r * g0.y + b0.y;
    o0.z = s0.z + d[2] * r * g0.z + b0.z;
    o0.w = s0.w + d[3] * r * g0.w + b0.w;
    o1.x = s1.x + d[4] * r * g1.x + b1.x;
    o1.y = s1.y + d[5] * r * g1.y + b1.y;
    o1.z = s1.z + d[6] * r * g1.z + b1.z;
    o1.w = s1.w + d[7] * r * g1.w + b1.w;
    *(float4*)(outp + (long)n * DIM + c8) = o0;
    *(float4*)(outp + (long)n * DIM + c8 + 4) = o1;
  }
}

// ---------------- launch ----------------
extern "C" void kernel_launch(void* const* d_in, const int* in_sizes, int n_in,
                              void* d_out, int out_size, void* d_ws, size_t ws_size,
                              hipStream_t stream) {
  (void)in_sizes; (void)n_in; (void)out_size; (void)ws_size;
  const int*   ei  = (const int*)d_in[0];
  const float* x0  = (const float*)d_in[1];
  const float* ea  = (const float*)d_in[2];
  const float* Wq  = (const float*)d_in[3];  const float* bq = (const float*)d_in[4];
  const float* Wk  = (const float*)d_in[5];  const float* bk = (const float*)d_in[6];
  const float* Wv  = (const float*)d_in[7];  const float* bv = (const float*)d_in[8];
  const float* We  = (const float*)d_in[9];  const float* be = (const float*)d_in[10];
  const float* Wsk = (const float*)d_in[11]; const float* bsk = (const float*)d_in[12];
  const float* W1  = (const float*)d_in[13]; const float* b1 = (const float*)d_in[14];
  const float* W2  = (const float*)d_in[15]; const float* b2 = (const float*)d_in[16];
  const float* g1  = (const float*)d_in[17]; const float* lb1 = (const float*)d_in[18];
  const float* g2  = (const float*)d_in[19]; const float* lb2 = (const float*)d_in[20];

  char* ws = (char*)d_ws;
  f16*   Qn     = (f16*)(ws + 0);              // 12.8M
  f16*   Kn     = (f16*)(ws + 12800000L);      // 12.8M
  f16*   Vn     = (f16*)(ws + 25600000L);      // 12.8M
  float* Skip   = (float*)(ws + 38400000L);    // 25.6M -> 64,000,000
  int*   offs   = (int*)(ws + 64000000L);      // 200,192
  f16*   WhAll  = (f16*)(ws + 64200192L);      // 229,376 (overlays cursor, dead after CSR)
  int*   cursor = (int*)(ws + 64200192L);
  int*   counts = (int*)(ws + 64429568L);      // 200,000
  int*   bsum   = (int*)(ws + 64629760L);      // 512 B
  int*   boff   = bsum + 64;
  int*   elist  = (int*)(ws + 64630272L);      // 3.2M
  int*   srcs   = (int*)(ws + 67830272L);      // 3.2M
  f16*   emat   = (f16*)(ws + 71030272L);      // 204.8M (dst-sorted)
  float* node1  = (float*)(ws + 275830272L);   // 25.6M

  // NOTE: WhAll overlays cursor in ws; hist_conv writes WhAll BEFORE expand_k writes
  // cursor — conflict! Move WhAll to its own slot after node1 instead.
  f16* WhAll2 = (f16*)(ws + 301430272L);       // 229,376 own slot (no overlay)

  (void)hipMemsetAsync(counts, 0, N_NODES * sizeof(int), stream);
  hist_conv_k<<<1024, 256, 0, stream>>>(ei, counts, Wq, Wk, Wv, Wsk, We, W1, W2, WhAll2);
  blocksum_k<<<SCAN_NB, 1024, 0, stream>>>(counts, bsum);
  scan_small<<<1, 64, 0, stream>>>(bsum, boff, offs);
  expand_k<<<SCAN_NB, 1024, 0, stream>>>(counts, boff, offs, cursor);
  scatter_k<<<1024, 256, 0, stream>>>(ei, cursor, elist, srcs);

  big_gemms<<<NODE_TILES + EDGE_BLOCKS, 256, 0, stream>>>(
      x0, ea, elist, WhAll2, bq, bk, bv, bsk, be, Qn, Kn, Vn, Skip, emat);
  attn_ln<<<12500, 256, 0, stream>>>(offs, srcs, emat, Qn, Kn, Vn, Skip, x0, g1, lb1, node1);
  mlp_ln<<<NODE_TILES, 256, 0, stream>>>(node1, WhAll2 + 5 * 16384, b1,
                                         WhAll2 + 6 * 16384, b2, g2, lb2, (float*)d_out);
}

// Round 16
// 469.465 us; speedup vs baseline: 1.8619x; 1.0049x over previous
//
#include <hip/hip_runtime.h>
#include <hip/hip_fp16.h>

#define N_NODES 50000
#define N_EDGES 800000
#define DIM 128
#define NODE_TILES 782   // ceil(50000/64)
#define EDGE_TILES 12500 // 800000/64
#define SCAN_NB 50       // 50 blocks x 1000 counts

typedef _Float16 f16;
typedef _Float16 f16x2 __attribute__((ext_vector_type(2)));
typedef _Float16 f16x4 __attribute__((ext_vector_type(4)));
typedef _Float16 f16x8 __attribute__((ext_vector_type(8)));
typedef float    f32x16 __attribute__((ext_vector_type(16)));

__device__ __forceinline__ void sfence() { __builtin_amdgcn_sched_barrier(0); }

// ---------------- shared GEMM pieces ----------------
__device__ __forceinline__ void load_wfrag(const f16* __restrict__ Wh, int ch, int l31, int g,
                                           f16x8 bf[2][8]) {
#pragma unroll
  for (int c = 0; c < 2; ++c)
#pragma unroll
    for (int ks = 0; ks < 8; ++ks)
      bf[c][ks] = *(const f16x8*)(Wh + ((ch * 64 + c * 32 + l31) << 7) + 16 * ks + 8 * g);
}

template <int HALF_OUT, int SILU>
__device__ __forceinline__ void gemm_store(f32x16 acc[2], long M, const float* __restrict__ Bv,
                                           void* __restrict__ OUT,
                                           long tile0, int rc, int ch, int l31, int g) {
#pragma unroll
  for (int c = 0; c < 2; ++c) {
    int col = ch * 64 + c * 32 + l31;
    float bv = Bv[col];
#pragma unroll
    for (int r = 0; r < 16; ++r) {
      long gm = tile0 + rc * 32 + ((r & 3) + 8 * (r >> 2) + 4 * g);
      if (gm < M) {
        float v = acc[c][r] + bv;
        if (SILU) v = v / (1.0f + __expf(-v));
        if (HALF_OUT) ((f16*)OUT)[gm * DIM + col] = (f16)v;
        else          ((float*)OUT)[gm * DIM + col] = v;
      }
    }
  }
}

// ---------------- staging: coalesced, f32->f16, XOR-swizzled LDS ----------------
__device__ __forceinline__ void stage_issue(const float* __restrict__ X, long M, long base,
                                            int tid, float4 sv[8]) {
#pragma unroll
  for (int kk = 0; kk < 8; ++kk) {
    int i = tid + kk * 256;
    long row = base + (i >> 5);
    long gr = row < M ? row : (M - 1);
    sv[kk] = *(const float4*)(X + gr * DIM + (i & 31) * 4);
  }
}

__device__ __forceinline__ void stage_issue_g(const float* __restrict__ X,
                                              const int* __restrict__ elist, long base,
                                              int tid, float4 sv[8]) {
#pragma unroll
  for (int kk = 0; kk < 8; ++kk) {
    int i = tid + kk * 256;
    int eid = elist[base + (i >> 5)];
    sv[kk] = *(const float4*)(X + (long)eid * DIM + (i & 31) * 4);
  }
}

__device__ __forceinline__ void stage_write(const float4 sv[8], int tid, f16* __restrict__ lds) {
#pragma unroll
  for (int kk = 0; kk < 8; ++kk) {
    int i = tid + kk * 256;
    int r = i >> 5, s8 = i & 31;
    f16x4 h;
    h[0] = (f16)sv[kk].x; h[1] = (f16)sv[kk].y; h[2] = (f16)sv[kk].z; h[3] = (f16)sv[kk].w;
    *(f16x4*)(lds + r * 128 + (((s8 >> 1) ^ (r & 15)) << 3) + ((s8 & 1) << 2)) = h;
  }
}

__device__ __forceinline__ void mfma_lds_g(const f16* __restrict__ A, int lr, int g,
                                           const f16x8 bf[2][8], f32x16 acc[2]) {
#pragma unroll
  for (int c = 0; c < 2; ++c)
#pragma unroll
    for (int k = 0; k < 16; ++k) acc[c][k] = 0.0f;
#pragma unroll
  for (int ks = 0; ks < 8; ++ks) {
    f16x8 a = *(const f16x8*)(A + lr * 128 + (((2 * ks + g) ^ (lr & 15)) << 3));
    acc[0] = __builtin_amdgcn_mfma_f32_32x32x16_f16(a, bf[0][ks], acc[0], 0, 0, 0);
    acc[1] = __builtin_amdgcn_mfma_f32_32x32x16_f16(a, bf[1][ks], acc[1], 0, 0, 0);
  }
}

// ---------------- fused big GEMMs, one tile per block (max TLP) ----------------
// blocks 0..781: node4 path (X tile staged once, 4 weight mats)
// blocks 782..13281: edge path (one gathered 64-edge tile each, no persistence)
__global__ __launch_bounds__(256) void big_gemms(const float* __restrict__ X,
    const float* __restrict__ EA, const int* __restrict__ elist,
    const f16* __restrict__ WhAll,
    const float* __restrict__ bq, const float* __restrict__ bk,
    const float* __restrict__ bv_, const float* __restrict__ bs, const float* __restrict__ be,
    f16* __restrict__ Q, f16* __restrict__ K, f16* __restrict__ V, float* __restrict__ S,
    f16* __restrict__ emat) {
  __shared__ f16 lbuf[64 * 128];      // 16 KB, both paths
  int tid = threadIdx.x;
  int lane = tid & 63, w = tid >> 6;
  int rc = w >> 1, ch = w & 1, l31 = lane & 31, g = lane >> 5;
  int lr = rc * 32 + l31;

  if (blockIdx.x < NODE_TILES) {
    long tile0 = (long)blockIdx.x * 64;
    float4 sv[8];
    stage_issue(X, N_NODES, tile0, tid, sv);
    stage_write(sv, tid, lbuf);
    __syncthreads();
#pragma unroll 1
    for (int mat = 0; mat < 4; ++mat) {
      f16x8 bf[2][8];
      load_wfrag(WhAll + mat * 16384, ch, l31, g, bf);
      f32x16 acc[2];
      mfma_lds_g(lbuf, lr, g, bf, acc);
      if (mat == 0)      gemm_store<1, 0>(acc, N_NODES, bq, Q, tile0, rc, ch, l31, g);
      else if (mat == 1) gemm_store<1, 0>(acc, N_NODES, bk, K, tile0, rc, ch, l31, g);
      else if (mat == 2) gemm_store<1, 0>(acc, N_NODES, bv_, V, tile0, rc, ch, l31, g);
      else               gemm_store<0, 0>(acc, N_NODES, bs, S, tile0, rc, ch, l31, g);
    }
    return;
  }

  // ---- edge path: one tile, one-shot ----
  long tile0 = (long)(blockIdx.x - NODE_TILES) * 64;
  float4 sv[8];
  stage_issue_g(EA, elist, tile0, tid, sv);
  sfence();
  stage_write(sv, tid, lbuf);          // waits on the gather loads
  __syncthreads();
  f16x8 bf[2][8];
  load_wfrag(WhAll + 4 * 16384, ch, l31, g, bf);  // L2-hot, after stage (lower peak VGPR)
  f32x16 acc[2];
  mfma_lds_g(lbuf, lr, g, bf, acc);
  gemm_store<1, 0>(acc, (long)N_EDGES, be, emat, tile0, rc, ch, l31, g);
}

// ---------------- fused MLP + LN2 (single 32 KB LDS, phase-aliased) ----------------
__global__ __launch_bounds__(256) void mlp_ln(const float* __restrict__ X,
    const f16* __restrict__ W1h, const float* __restrict__ b1,
    const f16* __restrict__ W2h, const float* __restrict__ b2,
    const float* __restrict__ gv, const float* __restrict__ bv,
    float* __restrict__ outp) {
  __shared__ float smem[64 * 128];    // 32 KB
  f16* xs = (f16*)smem;               // first 16 KB
  f16* hs = (f16*)smem + 64 * 128;    // second 16 KB
  float* wbuf = smem;                 // full 32 KB
  int tid = threadIdx.x;
  int lane = tid & 63, w = tid >> 6;
  int rc = w >> 1, ch = w & 1, l31 = lane & 31, g = lane >> 5;
  int t = blockIdx.x;
  if (t >= NODE_TILES) return;
  long tile0 = (long)t * 64;
  int lr = rc * 32 + l31;

  float4 sv[8];
  stage_issue(X, N_NODES, tile0, tid, sv);
  f16x8 bf1[2][8];
  load_wfrag(W1h, ch, l31, g, bf1);
  stage_write(sv, tid, xs);
  __syncthreads();

  f32x16 acc[2];
  mfma_lds_g(xs, lr, g, bf1, acc);
  f16x8 bf2[2][8];
  load_wfrag(W2h, ch, l31, g, bf2);

#pragma unroll
  for (int c = 0; c < 2; ++c) {
    int col = ch * 64 + c * 32 + l31;
    float bb = b1[col];
#pragma unroll
    for (int r = 0; r < 16; ++r) {
      int row = rc * 32 + (r & 3) + 8 * (r >> 2) + 4 * g;
      float v = acc[c][r] + bb;
      v = v / (1.0f + __expf(-v));
      hs[row * 128 + (((col >> 3) ^ (row & 15)) << 3) + (col & 7)] = (f16)v;
    }
  }
  __syncthreads();

  f32x16 a2[2];
  mfma_lds_g(hs, lr, g, bf2, a2);
  __syncthreads();

#pragma unroll
  for (int c = 0; c < 2; ++c) {
    int col = ch * 64 + c * 32 + l31;
    float bb = b2[col];
#pragma unroll
    for (int r = 0; r < 16; ++r) {
      int row = rc * 32 + (r & 3) + 8 * (r >> 2) + 4 * g;
      wbuf[row * 128 + col] = a2[c][r] + bb;
    }
  }
  __syncthreads();

  float2 gg = *(const float2*)(gv + 2 * lane);
  float2 bb2 = *(const float2*)(bv + 2 * lane);
#pragma unroll 1
  for (int rr = 0; rr < 16; ++rr) {
    int row = w * 16 + rr;
    long gm = tile0 + row;
    if (gm >= N_NODES) break;
    float2 x;
    x.x = wbuf[row * 128 + 2 * lane];
    x.y = wbuf[row * 128 + 2 * lane + 1];
    float sm = x.x + x.y;
    for (int m = 1; m < 64; m <<= 1) sm += __shfl_xor(sm, m);
    float mu = sm * (1.f / 128.f);
    float dx = x.x - mu, dy = x.y - mu;
    float ss = dx * dx + dy * dy;
    for (int m = 1; m < 64; m <<= 1) ss += __shfl_xor(ss, m);
    float r = rsqrtf(ss * (1.f / 128.f) + 1e-5f);
    float2 bs = *(const float2*)(X + gm * DIM + 2 * lane);
    float2 o;
    o.x = bs.x + dx * r * gg.x + bb2.x;
    o.y = bs.y + dy * r * gg.y + bb2.y;
    *(float2*)(outp + gm * DIM + 2 * lane) = o;
  }
}

// ---------------- CSR build (parallel scan) + weight convert fused into hist ----------
__global__ void hist_conv_k(const int* __restrict__ ei, int* __restrict__ counts,
                            const float* __restrict__ a0, const float* __restrict__ a1,
                            const float* __restrict__ a2, const float* __restrict__ a3,
                            const float* __restrict__ a4, const float* __restrict__ a5,
                            const float* __restrict__ a6, f16* __restrict__ dst) {
  long gid = blockIdx.x * 256L + threadIdx.x;
  if (gid < 7 * 16384) {
    int mat = (int)(gid >> 14), el = (int)(gid & 16383);
    const float* s = (mat == 0) ? a0 : (mat == 1) ? a1 : (mat == 2) ? a2 : (mat == 3) ? a3
                   : (mat == 4) ? a4 : (mat == 5) ? a5 : a6;
    dst[gid] = (f16)s[el];
  }
  for (long e = gid; e < N_EDGES; e += 1024L * 256)
    atomicAdd(&counts[ei[N_EDGES + e]], 1);
}

__global__ __launch_bounds__(1024) void blocksum_k(const int* __restrict__ counts,
                                                   int* __restrict__ bsum) {
  __shared__ int sd[1024];
  int t = threadIdx.x, b = blockIdx.x;
  int v = (t < 1000) ? counts[b * 1000 + t] : 0;
  sd[t] = v; __syncthreads();
  for (int off = 512; off > 0; off >>= 1) {
    if (t < off) sd[t] += sd[t + off];
    __syncthreads();
  }
  if (t == 0) bsum[b] = sd[0];
}

__global__ void scan_small(const int* __restrict__ bsum, int* __restrict__ boff,
                           int* __restrict__ offs) {
  if (threadIdx.x == 0) {
    int run = 0;
    for (int b = 0; b < SCAN_NB; ++b) { boff[b] = run; run += bsum[b]; }
    boff[SCAN_NB] = run;
    offs[N_NODES] = run;
  }
}

__global__ __launch_bounds__(1024) void expand_k(const int* __restrict__ counts,
                                                 const int* __restrict__ boff,
                                                 int* __restrict__ offs, int* __restrict__ cursor) {
  __shared__ int sd[1024];
  int t = threadIdx.x, b = blockIdx.x;
  int v = (t < 1000) ? counts[b * 1000 + t] : 0;
  sd[t] = v; __syncthreads();
  for (int off = 1; off < 1024; off <<= 1) {
    int x = (t >= off) ? sd[t - off] : 0;
    __syncthreads();
    sd[t] += x;
    __syncthreads();
  }
  if (t < 1000) {
    int o = boff[b] + sd[t] - v;
    int idx = b * 1000 + t;
    offs[idx] = o;
    cursor[idx] = o;
  }
}

__global__ void scatter_k(const int* __restrict__ ei, int* __restrict__ cursor,
                          int* __restrict__ elist, int* __restrict__ srcs) {
  for (long e = blockIdx.x * (long)blockDim.x + threadIdx.x; e < N_EDGES;
       e += (long)gridDim.x * blockDim.x) {
    int d = ei[N_EDGES + e];
    int pos = atomicAdd(&cursor[d], 1);
    elist[pos] = (int)e;
    srcs[pos] = ei[e];
  }
}

// ---------------- fused attention + softmax + LN1, 4 edges/iteration ----------------
__global__ __launch_bounds__(256) void attn_ln(const int* __restrict__ offs,
    const int* __restrict__ srcs, const f16* __restrict__ emat, const f16* __restrict__ Qn,
    const f16* __restrict__ Kn, const f16* __restrict__ Vn,
    const float* __restrict__ Skip, const float* __restrict__ base,
    const float* __restrict__ gv, const float* __restrict__ bv,
    float* __restrict__ outp) {
  int n = blockIdx.x * 4 + (threadIdx.x >> 6);
  if (n >= N_NODES) return;
  int lane = threadIdx.x & 63;
  int grp = lane >> 4, li = lane & 15;
  int c8 = 8 * li;

  float q[8];
  {
    f16x8 qv = *(const f16x8*)(Qn + (long)n * DIM + c8);
#pragma unroll
    for (int k = 0; k < 8; ++k) q[k] = (float)qv[k];
  }

  int rs = offs[n], re = offs[n + 1];
  float a[8];
#pragma unroll
  for (int k = 0; k < 8; ++k) a[k] = 0.f;
  float den = 0.f;

  if (rs < re) {
    int e0 = rs + grp;
    int sCur = srcs[(e0 < re) ? e0 : (re - 1)];
    for (int i = rs; i < re; i += 4) {
      int ei_ = i + grp;
      bool valid = ei_ < re;
      int ec = valid ? ei_ : (re - 1);
      int s = sCur;
      int en = ei_ + 4;
      sCur = srcs[(en < re) ? en : (re - 1)];
      f16x8 e8 = *(const f16x8*)(emat + (long)ec * DIM + c8);
      f16x8 k8 = *(const f16x8*)(Kn + (long)s * DIM + c8);
      f16x8 v8 = *(const f16x8*)(Vn + (long)s * DIM + c8);
      float p = 0.f;
#pragma unroll
      for (int k = 0; k < 8; ++k) p += q[k] * ((float)k8[k] + (float)e8[k]);
      p += __shfl_xor(p, 1);
      float ex = valid ? __expf(p * 0.25f) : 0.f;
      den += ex;
#pragma unroll
      for (int k = 0; k < 8; ++k) a[k] += ex * ((float)e8[k] + (float)v8[k]);
    }
  }
#pragma unroll
  for (int k = 0; k < 8; ++k) {
    a[k] += __shfl_xor(a[k], 16);
    a[k] += __shfl_xor(a[k], 32);
  }
  den += __shfl_xor(den, 16);
  den += __shfl_xor(den, 32);

  float inv = 1.f / (den + 1e-16f);
  float x[8];
  {
    float4 sk0 = *(const float4*)(Skip + (long)n * DIM + c8);
    float4 sk1 = *(const float4*)(Skip + (long)n * DIM + c8 + 4);
    x[0] = a[0] * inv + sk0.x; x[1] = a[1] * inv + sk0.y;
    x[2] = a[2] * inv + sk0.z; x[3] = a[3] * inv + sk0.w;
    x[4] = a[4] * inv + sk1.x; x[5] = a[5] * inv + sk1.y;
    x[6] = a[6] * inv + sk1.z; x[7] = a[7] * inv + sk1.w;
  }

  float sm = 0.f;
#pragma unroll
  for (int k = 0; k < 8; ++k) sm += x[k];
  for (int m = 1; m < 16; m <<= 1) sm += __shfl_xor(sm, m);
  float mu = sm * (1.f / 128.f);
  float d[8], ss = 0.f;
#pragma unroll
  for (int k = 0; k < 8; ++k) { d[k] = x[k] - mu; ss += d[k] * d[k]; }
  for (int m = 1; m < 16; m <<= 1) ss += __shfl_xor(ss, m);
  float r = rsqrtf(ss * (1.f / 128.f) + 1e-5f);

  if (grp == 0) {
    float4 g0 = *(const float4*)(gv + c8);
    float4 g1 = *(const float4*)(gv + c8 + 4);
    float4 b0 = *(const float4*)(bv + c8);
    float4 b1 = *(const float4*)(bv + c8 + 4);
    float4 s0 = *(const float4*)(base + (long)n * DIM + c8);
    float4 s1 = *(const float4*)(base + (long)n * DIM + c8 + 4);
    float4 o0, o1;
    o0.x = s0.x + d[0] * r * g0.x + b0.x;
    o0.y = s0.y + d[1] * r * g0.y + b0.y;
    o0.z = s0.z + d[2] * r * g0.z + b0.z;
    o0.w = s0.w + d[3] * r * g0.w + b0.w;
    o1.x = s1.x + d[4] * r * g1.x + b1.x;
    o1.y = s1.y + d[5] * r * g1.y + b1.y;
    o1.z = s1.z + d[6] * r * g1.z + b1.z;
    o1.w = s1.w + d[7] * r * g1.w + b1.w;
    *(float4*)(outp + (long)n * DIM + c8) = o0;
    *(float4*)(outp + (long)n * DIM + c8 + 4) = o1;
  }
}

// ---------------- launch ----------------
extern "C" void kernel_launch(void* const* d_in, const int* in_sizes, int n_in,
                              void* d_out, int out_size, void* d_ws, size_t ws_size,
                              hipStream_t stream) {
  (void)in_sizes; (void)n_in; (void)out_size; (void)ws_size;
  const int*   ei  = (const int*)d_in[0];
  const float* x0  = (const float*)d_in[1];
  const float* ea  = (const float*)d_in[2];
  const float* Wq  = (const float*)d_in[3];  const float* bq = (const float*)d_in[4];
  const float* Wk  = (const float*)d_in[5];  const float* bk = (const float*)d_in[6];
  const float* Wv  = (const float*)d_in[7];  const float* bv = (const float*)d_in[8];
  const float* We  = (const float*)d_in[9];  const float* be = (const float*)d_in[10];
  const float* Wsk = (const float*)d_in[11]; const float* bsk = (const float*)d_in[12];
  const float* W1  = (const float*)d_in[13]; const float* b1 = (const float*)d_in[14];
  const float* W2  = (const float*)d_in[15]; const float* b2 = (const float*)d_in[16];
  const float* g1  = (const float*)d_in[17]; const float* lb1 = (const float*)d_in[18];
  const float* g2  = (const float*)d_in[19]; const float* lb2 = (const float*)d_in[20];

  char* ws = (char*)d_ws;
  f16*   Qn     = (f16*)(ws + 0);              // 12.8M
  f16*   Kn     = (f16*)(ws + 12800000L);      // 12.8M
  f16*   Vn     = (f16*)(ws + 25600000L);      // 12.8M
  float* Skip   = (float*)(ws + 38400000L);    // 25.6M -> 64,000,000
  int*   offs   = (int*)(ws + 64000000L);      // 200,192
  int*   cursor = (int*)(ws + 64200192L);      // 200,192
  int*   counts = (int*)(ws + 64429568L);      // 200,000
  int*   bsum   = (int*)(ws + 64629760L);      // 512 B
  int*   boff   = bsum + 64;
  int*   elist  = (int*)(ws + 64630272L);      // 3.2M
  int*   srcs   = (int*)(ws + 67830272L);      // 3.2M
  f16*   emat   = (f16*)(ws + 71030272L);      // 204.8M (dst-sorted)
  float* node1  = (float*)(ws + 275830272L);   // 25.6M
  f16*   WhAll  = (f16*)(ws + 301430272L);     // 229,376 own slot (no overlay)

  (void)hipMemsetAsync(counts, 0, N_NODES * sizeof(int), stream);
  hist_conv_k<<<1024, 256, 0, stream>>>(ei, counts, Wq, Wk, Wv, Wsk, We, W1, W2, WhAll);
  blocksum_k<<<SCAN_NB, 1024, 0, stream>>>(counts, bsum);
  scan_small<<<1, 64, 0, stream>>>(bsum, boff, offs);
  expand_k<<<SCAN_NB, 1024, 0, stream>>>(counts, boff, offs, cursor);
  scatter_k<<<1024, 256, 0, stream>>>(ei, cursor, elist, srcs);

  big_gemms<<<NODE_TILES + EDGE_TILES, 256, 0, stream>>>(
      x0, ea, elist, WhAll, bq, bk, bv, bsk, be, Qn, Kn, Vn, Skip, emat);
  attn_ln<<<12500, 256, 0, stream>>>(offs, srcs, emat, Qn, Kn, Vn, Skip, x0, g1, lb1, node1);
  mlp_ln<<<NODE_TILES, 256, 0, stream>>>(node1, WhAll + 5 * 16384, b1,
                                         WhAll + 6 * 16384, b2, g2, lb2, (float*)d_out);
}

// Round 17
// 456.034 us; speedup vs baseline: 1.9167x; 1.0295x over previous
//
#include <hip/hip_runtime.h>
#include <hip/hip_fp16.h>

#define N_NODES 50000
#define N_EDGES 800000
#define DIM 128
#define NODE_TILES 782   // ceil(50000/64)
#define EDGE_TILES 12500 // 800000/64
#define SCAN_NB 50       // 50 blocks x 1000 counts

typedef _Float16 f16;
typedef _Float16 f16x2 __attribute__((ext_vector_type(2)));
typedef _Float16 f16x4 __attribute__((ext_vector_type(4)));
typedef _Float16 f16x8 __attribute__((ext_vector_type(8)));
typedef float    f32x16 __attribute__((ext_vector_type(16)));

__device__ __forceinline__ void sfence() { __builtin_amdgcn_sched_barrier(0); }

// ---------------- 256-thread (4-wave) GEMM pieces — used by mlp_ln ----------------
__device__ __forceinline__ void load_wfrag(const f16* __restrict__ Wh, int ch, int l31, int g,
                                           f16x8 bf[2][8]) {
#pragma unroll
  for (int c = 0; c < 2; ++c)
#pragma unroll
    for (int ks = 0; ks < 8; ++ks)
      bf[c][ks] = *(const f16x8*)(Wh + ((ch * 64 + c * 32 + l31) << 7) + 16 * ks + 8 * g);
}

__device__ __forceinline__ void stage_issue(const float* __restrict__ X, long M, long base,
                                            int tid, float4 sv[8]) {
#pragma unroll
  for (int kk = 0; kk < 8; ++kk) {
    int i = tid + kk * 256;
    long row = base + (i >> 5);
    long gr = row < M ? row : (M - 1);
    sv[kk] = *(const float4*)(X + gr * DIM + (i & 31) * 4);
  }
}

__device__ __forceinline__ void stage_write(const float4 sv[8], int tid, f16* __restrict__ lds) {
#pragma unroll
  for (int kk = 0; kk < 8; ++kk) {
    int i = tid + kk * 256;
    int r = i >> 5, s8 = i & 31;
    f16x4 h;
    h[0] = (f16)sv[kk].x; h[1] = (f16)sv[kk].y; h[2] = (f16)sv[kk].z; h[3] = (f16)sv[kk].w;
    *(f16x4*)(lds + r * 128 + (((s8 >> 1) ^ (r & 15)) << 3) + ((s8 & 1) << 2)) = h;
  }
}

__device__ __forceinline__ void mfma_lds_g(const f16* __restrict__ A, int lr, int g,
                                           const f16x8 bf[2][8], f32x16 acc[2]) {
#pragma unroll
  for (int c = 0; c < 2; ++c)
#pragma unroll
    for (int k = 0; k < 16; ++k) acc[c][k] = 0.0f;
#pragma unroll
  for (int ks = 0; ks < 8; ++ks) {
    f16x8 a = *(const f16x8*)(A + lr * 128 + (((2 * ks + g) ^ (lr & 15)) << 3));
    acc[0] = __builtin_amdgcn_mfma_f32_32x32x16_f16(a, bf[0][ks], acc[0], 0, 0, 0);
    acc[1] = __builtin_amdgcn_mfma_f32_32x32x16_f16(a, bf[1][ks], acc[1], 0, 0, 0);
  }
}

// ---------------- 512-thread (8-wave) GEMM pieces — one 32x32 block per wave ------
__device__ __forceinline__ void load_wfrag1(const f16* __restrict__ Wh, int cc, int l31, int g,
                                            f16x8 bf[8]) {
#pragma unroll
  for (int ks = 0; ks < 8; ++ks)
    bf[ks] = *(const f16x8*)(Wh + ((cc * 32 + l31) << 7) + 16 * ks + 8 * g);
}

__device__ __forceinline__ void stage_issue512(const float* __restrict__ X, long M, long base,
                                               int tid, float4 sv[4]) {
#pragma unroll
  for (int kk = 0; kk < 4; ++kk) {
    int i = tid + kk * 512;
    long row = base + (i >> 5);
    long gr = row < M ? row : (M - 1);
    sv[kk] = *(const float4*)(X + gr * DIM + (i & 31) * 4);
  }
}

__device__ __forceinline__ void stage_issue_g512(const float* __restrict__ X,
                                                 const int* __restrict__ elist, long base,
                                                 int tid, float4 sv[4]) {
#pragma unroll
  for (int kk = 0; kk < 4; ++kk) {
    int i = tid + kk * 512;
    int eid = elist[base + (i >> 5)];
    sv[kk] = *(const float4*)(X + (long)eid * DIM + (i & 31) * 4);
  }
}

__device__ __forceinline__ void stage_write512(const float4 sv[4], int tid,
                                               f16* __restrict__ lds) {
#pragma unroll
  for (int kk = 0; kk < 4; ++kk) {
    int i = tid + kk * 512;
    int r = i >> 5, s8 = i & 31;
    f16x4 h;
    h[0] = (f16)sv[kk].x; h[1] = (f16)sv[kk].y; h[2] = (f16)sv[kk].z; h[3] = (f16)sv[kk].w;
    *(f16x4*)(lds + r * 128 + (((s8 >> 1) ^ (r & 15)) << 3) + ((s8 & 1) << 2)) = h;
  }
}

__device__ __forceinline__ void mfma1(const f16* __restrict__ A, int lr, int g,
                                      const f16x8 bf[8], f32x16& acc) {
#pragma unroll
  for (int k = 0; k < 16; ++k) acc[k] = 0.0f;
#pragma unroll
  for (int ks = 0; ks < 8; ++ks) {
    f16x8 a = *(const f16x8*)(A + lr * 128 + (((2 * ks + g) ^ (lr & 15)) << 3));
    acc = __builtin_amdgcn_mfma_f32_32x32x16_f16(a, bf[ks], acc, 0, 0, 0);
  }
}

template <int HALF_OUT>
__device__ __forceinline__ void gemm_store1(const f32x16& acc, long M,
                                            const float* __restrict__ Bv,
                                            void* __restrict__ OUT,
                                            long tile0, int rc, int cc, int l31, int g) {
  int col = cc * 32 + l31;
  float bv = Bv[col];
#pragma unroll
  for (int r = 0; r < 16; ++r) {
    long gm = tile0 + rc * 32 + ((r & 3) + 8 * (r >> 2) + 4 * g);
    if (gm < M) {
      float v = acc[r] + bv;
      if (HALF_OUT) ((f16*)OUT)[gm * DIM + col] = (f16)v;
      else          ((float*)OUT)[gm * DIM + col] = v;
    }
  }
}

// ---------------- fused big GEMMs, 512 threads, one tile per block ----------------
// blocks 0..781: node4 path; blocks 782..13281: edge path (one 64-edge tile each).
// 8 waves x (32x32 output) per block; VGPR budget < 128 -> 16 waves/CU.
__global__ __launch_bounds__(512, 4) void big_gemms(const float* __restrict__ X,
    const float* __restrict__ EA, const int* __restrict__ elist,
    const f16* __restrict__ WhAll,
    const float* __restrict__ bq, const float* __restrict__ bk,
    const float* __restrict__ bv_, const float* __restrict__ bs, const float* __restrict__ be,
    f16* __restrict__ Q, f16* __restrict__ K, f16* __restrict__ V, float* __restrict__ S,
    f16* __restrict__ emat) {
  __shared__ f16 lbuf[64 * 128];      // 16 KB
  int tid = threadIdx.x;
  int lane = tid & 63, w = tid >> 6;
  int rc = w >> 2, cc = w & 3, l31 = lane & 31, g = lane >> 5;
  int lr = rc * 32 + l31;

  if (blockIdx.x < NODE_TILES) {
    long tile0 = (long)blockIdx.x * 64;
    float4 sv[4];
    stage_issue512(X, N_NODES, tile0, tid, sv);
    stage_write512(sv, tid, lbuf);
    __syncthreads();
#pragma unroll 1
    for (int mat = 0; mat < 4; ++mat) {
      f16x8 bf[8];
      load_wfrag1(WhAll + mat * 16384, cc, l31, g, bf);
      f32x16 acc;
      mfma1(lbuf, lr, g, bf, acc);
      if (mat == 0)      gemm_store1<1>(acc, N_NODES, bq, Q, tile0, rc, cc, l31, g);
      else if (mat == 1) gemm_store1<1>(acc, N_NODES, bk, K, tile0, rc, cc, l31, g);
      else if (mat == 2) gemm_store1<1>(acc, N_NODES, bv_, V, tile0, rc, cc, l31, g);
      else               gemm_store1<0>(acc, N_NODES, bs, S, tile0, rc, cc, l31, g);
    }
    return;
  }

  // ---- edge path: one gathered 64-edge tile, one-shot ----
  long tile0 = (long)(blockIdx.x - NODE_TILES) * 64;
  float4 sv[4];
  stage_issue_g512(EA, elist, tile0, tid, sv);
  sfence();
  stage_write512(sv, tid, lbuf);
  __syncthreads();
  f16x8 bf[8];
  load_wfrag1(WhAll + 4 * 16384, cc, l31, g, bf);   // L2-hot, after stage
  f32x16 acc;
  mfma1(lbuf, lr, g, bf, acc);
  gemm_store1<1>(acc, (long)N_EDGES, be, emat, tile0, rc, cc, l31, g);
}

// ---------------- fused MLP + LN2 (single 32 KB LDS, phase-aliased) ----------------
__global__ __launch_bounds__(256) void mlp_ln(const float* __restrict__ X,
    const f16* __restrict__ W1h, const float* __restrict__ b1,
    const f16* __restrict__ W2h, const float* __restrict__ b2,
    const float* __restrict__ gv, const float* __restrict__ bv,
    float* __restrict__ outp) {
  __shared__ float smem[64 * 128];    // 32 KB
  f16* xs = (f16*)smem;               // first 16 KB
  f16* hs = (f16*)smem + 64 * 128;    // second 16 KB
  float* wbuf = smem;                 // full 32 KB
  int tid = threadIdx.x;
  int lane = tid & 63, w = tid >> 6;
  int rc = w >> 1, ch = w & 1, l31 = lane & 31, g = lane >> 5;
  int t = blockIdx.x;
  if (t >= NODE_TILES) return;
  long tile0 = (long)t * 64;
  int lr = rc * 32 + l31;

  float4 sv[8];
  stage_issue(X, N_NODES, tile0, tid, sv);
  f16x8 bf1[2][8];
  load_wfrag(W1h, ch, l31, g, bf1);
  stage_write(sv, tid, xs);
  __syncthreads();

  f32x16 acc[2];
  mfma_lds_g(xs, lr, g, bf1, acc);
  f16x8 bf2[2][8];
  load_wfrag(W2h, ch, l31, g, bf2);

#pragma unroll
  for (int c = 0; c < 2; ++c) {
    int col = ch * 64 + c * 32 + l31;
    float bb = b1[col];
#pragma unroll
    for (int r = 0; r < 16; ++r) {
      int row = rc * 32 + (r & 3) + 8 * (r >> 2) + 4 * g;
      float v = acc[c][r] + bb;
      v = v / (1.0f + __expf(-v));
      hs[row * 128 + (((col >> 3) ^ (row & 15)) << 3) + (col & 7)] = (f16)v;
    }
  }
  __syncthreads();

  f32x16 a2[2];
  mfma_lds_g(hs, lr, g, bf2, a2);
  __syncthreads();

#pragma unroll
  for (int c = 0; c < 2; ++c) {
    int col = ch * 64 + c * 32 + l31;
    float bb = b2[col];
#pragma unroll
    for (int r = 0; r < 16; ++r) {
      int row = rc * 32 + (r & 3) + 8 * (r >> 2) + 4 * g;
      wbuf[row * 128 + col] = a2[c][r] + bb;
    }
  }
  __syncthreads();

  float2 gg = *(const float2*)(gv + 2 * lane);
  float2 bb2 = *(const float2*)(bv + 2 * lane);
#pragma unroll 1
  for (int rr = 0; rr < 16; ++rr) {
    int row = w * 16 + rr;
    long gm = tile0 + row;
    if (gm >= N_NODES) break;
    float2 x;
    x.x = wbuf[row * 128 + 2 * lane];
    x.y = wbuf[row * 128 + 2 * lane + 1];
    float sm = x.x + x.y;
    for (int m = 1; m < 64; m <<= 1) sm += __shfl_xor(sm, m);
    float mu = sm * (1.f / 128.f);
    float dx = x.x - mu, dy = x.y - mu;
    float ss = dx * dx + dy * dy;
    for (int m = 1; m < 64; m <<= 1) ss += __shfl_xor(ss, m);
    float r = rsqrtf(ss * (1.f / 128.f) + 1e-5f);
    float2 bs = *(const float2*)(X + gm * DIM + 2 * lane);
    float2 o;
    o.x = bs.x + dx * r * gg.x + bb2.x;
    o.y = bs.y + dy * r * gg.y + bb2.y;
    *(float2*)(outp + gm * DIM + 2 * lane) = o;
  }
}

// ---------------- CSR build (parallel scan) + weight convert fused into hist ----------
__global__ void hist_conv_k(const int* __restrict__ ei, int* __restrict__ counts,
                            const float* __restrict__ a0, const float* __restrict__ a1,
                            const float* __restrict__ a2, const float* __restrict__ a3,
                            const float* __restrict__ a4, const float* __restrict__ a5,
                            const float* __restrict__ a6, f16* __restrict__ dst) {
  long gid = blockIdx.x * 256L + threadIdx.x;
  if (gid < 7 * 16384) {
    int mat = (int)(gid >> 14), el = (int)(gid & 16383);
    const float* s = (mat == 0) ? a0 : (mat == 1) ? a1 : (mat == 2) ? a2 : (mat == 3) ? a3
                   : (mat == 4) ? a4 : (mat == 5) ? a5 : a6;
    dst[gid] = (f16)s[el];
  }
  for (long e = gid; e < N_EDGES; e += 1024L * 256)
    atomicAdd(&counts[ei[N_EDGES + e]], 1);
}

__global__ __launch_bounds__(1024) void blocksum_k(const int* __restrict__ counts,
                                                   int* __restrict__ bsum) {
  __shared__ int sd[1024];
  int t = threadIdx.x, b = blockIdx.x;
  int v = (t < 1000) ? counts[b * 1000 + t] : 0;
  sd[t] = v; __syncthreads();
  for (int off = 512; off > 0; off >>= 1) {
    if (t < off) sd[t] += sd[t + off];
    __syncthreads();
  }
  if (t == 0) bsum[b] = sd[0];
}

__global__ void scan_small(const int* __restrict__ bsum, int* __restrict__ boff,
                           int* __restrict__ offs) {
  if (threadIdx.x == 0) {
    int run = 0;
    for (int b = 0; b < SCAN_NB; ++b) { boff[b] = run; run += bsum[b]; }
    boff[SCAN_NB] = run;
    offs[N_NODES] = run;
  }
}

__global__ __launch_bounds__(1024) void expand_k(const int* __restrict__ counts,
                                                 const int* __restrict__ boff,
                                                 int* __restrict__ offs, int* __restrict__ cursor) {
  __shared__ int sd[1024];
  int t = threadIdx.x, b = blockIdx.x;
  int v = (t < 1000) ? counts[b * 1000 + t] : 0;
  sd[t] = v; __syncthreads();
  for (int off = 1; off < 1024; off <<= 1) {
    int x = (t >= off) ? sd[t - off] : 0;
    __syncthreads();
    sd[t] += x;
    __syncthreads();
  }
  if (t < 1000) {
    int o = boff[b] + sd[t] - v;
    int idx = b * 1000 + t;
    offs[idx] = o;
    cursor[idx] = o;
  }
}

__global__ void scatter_k(const int* __restrict__ ei, int* __restrict__ cursor,
                          int* __restrict__ elist, int* __restrict__ srcs) {
  for (long e = blockIdx.x * (long)blockDim.x + threadIdx.x; e < N_EDGES;
       e += (long)gridDim.x * blockDim.x) {
    int d = ei[N_EDGES + e];
    int pos = atomicAdd(&cursor[d], 1);
    elist[pos] = (int)e;
    srcs[pos] = ei[e];
  }
}

// ---------------- fused attention + softmax + LN1, 4 edges/iteration ----------------
__global__ __launch_bounds__(256) void attn_ln(const int* __restrict__ offs,
    const int* __restrict__ srcs, const f16* __restrict__ emat, const f16* __restrict__ Qn,
    const f16* __restrict__ Kn, const f16* __restrict__ Vn,
    const float* __restrict__ Skip, const float* __restrict__ base,
    const float* __restrict__ gv, const float* __restrict__ bv,
    float* __restrict__ outp) {
  int n = blockIdx.x * 4 + (threadIdx.x >> 6);
  if (n >= N_NODES) return;
  int lane = threadIdx.x & 63;
  int grp = lane >> 4, li = lane & 15;
  int c8 = 8 * li;

  float q[8];
  {
    f16x8 qv = *(const f16x8*)(Qn + (long)n * DIM + c8);
#pragma unroll
    for (int k = 0; k < 8; ++k) q[k] = (float)qv[k];
  }

  int rs = offs[n], re = offs[n + 1];
  float a[8];
#pragma unroll
  for (int k = 0; k < 8; ++k) a[k] = 0.f;
  float den = 0.f;

  if (rs < re) {
    int e0 = rs + grp;
    int sCur = srcs[(e0 < re) ? e0 : (re - 1)];
    for (int i = rs; i < re; i += 4) {
      int ei_ = i + grp;
      bool valid = ei_ < re;
      int ec = valid ? ei_ : (re - 1);
      int s = sCur;
      int en = ei_ + 4;
      sCur = srcs[(en < re) ? en : (re - 1)];
      f16x8 e8 = *(const f16x8*)(emat + (long)ec * DIM + c8);
      f16x8 k8 = *(const f16x8*)(Kn + (long)s * DIM + c8);
      f16x8 v8 = *(const f16x8*)(Vn + (long)s * DIM + c8);
      float p = 0.f;
#pragma unroll
      for (int k = 0; k < 8; ++k) p += q[k] * ((float)k8[k] + (float)e8[k]);
      p += __shfl_xor(p, 1);
      float ex = valid ? __expf(p * 0.25f) : 0.f;
      den += ex;
#pragma unroll
      for (int k = 0; k < 8; ++k) a[k] += ex * ((float)e8[k] + (float)v8[k]);
    }
  }
#pragma unroll
  for (int k = 0; k < 8; ++k) {
    a[k] += __shfl_xor(a[k], 16);
    a[k] += __shfl_xor(a[k], 32);
  }
  den += __shfl_xor(den, 16);
  den += __shfl_xor(den, 32);

  float inv = 1.f / (den + 1e-16f);
  float x[8];
  {
    float4 sk0 = *(const float4*)(Skip + (long)n * DIM + c8);
    float4 sk1 = *(const float4*)(Skip + (long)n * DIM + c8 + 4);
    x[0] = a[0] * inv + sk0.x; x[1] = a[1] * inv + sk0.y;
    x[2] = a[2] * inv + sk0.z; x[3] = a[3] * inv + sk0.w;
    x[4] = a[4] * inv + sk1.x; x[5] = a[5] * inv + sk1.y;
    x[6] = a[6] * inv + sk1.z; x[7] = a[7] * inv + sk1.w;
  }

  float sm = 0.f;
#pragma unroll
  for (int k = 0; k < 8; ++k) sm += x[k];
  for (int m = 1; m < 16; m <<= 1) sm += __shfl_xor(sm, m);
  float mu = sm * (1.f / 128.f);
  float d[8], ss = 0.f;
#pragma unroll
  for (int k = 0; k < 8; ++k) { d[k] = x[k] - mu; ss += d[k] * d[k]; }
  for (int m = 1; m < 16; m <<= 1) ss += __shfl_xor(ss, m);
  float r = rsqrtf(ss * (1.f / 128.f) + 1e-5f);

  if (grp == 0) {
    float4 g0 = *(const float4*)(gv + c8);
    float4 g1 = *(const float4*)(gv + c8 + 4);
    float4 b0 = *(const float4*)(bv + c8);
    float4 b1 = *(const float4*)(bv + c8 + 4);
    float4 s0 = *(const float4*)(base + (long)n * DIM + c8);
    float4 s1 = *(const float4*)(base + (long)n * DIM + c8 + 4);
    float4 o0, o1;
    o0.x = s0.x + d[0] * r * g0.x + b0.x;
    o0.y = s0.y + d[1] * r * g0.y + b0.y;
    o0.z = s0.z + d[2] * r * g0.z + b0.z;
    o0.w = s0.w + d[3] * r * g0.w + b0.w;
    o1.x = s1.x + d[4] * r * g1.x + b1.x;
    o1.y = s1.y + d[5] * r * g1.y + b1.y;
    o1.z = s1.z + d[6] * r * g1.z + b1.z;
    o1.w = s1.w + d[7] * r * g1.w + b1.w;
    *(float4*)(outp + (long)n * DIM + c8) = o0;
    *(float4*)(outp + (long)n * DIM + c8 + 4) = o1;
  }
}

// ---------------- launch ----------------
extern "C" void kernel_launch(void* const* d_in, const int* in_sizes, int n_in,
                              void* d_out, int out_size, void* d_ws, size_t ws_size,
                              hipStream_t stream) {
  (void)in_sizes; (void)n_in; (void)out_size; (void)ws_size;
  const int*   ei  = (const int*)d_in[0];
  const float* x0  = (const float*)d_in[1];
  const float* ea  = (const float*)d_in[2];
  const float* Wq  = (const float*)d_in[3];  const float* bq = (const float*)d_in[4];
  const float* Wk  = (const float*)d_in[5];  const float* bk = (const float*)d_in[6];
  const float* Wv  = (const float*)d_in[7];  const float* bv = (const float*)d_in[8];
  const float* We  = (const float*)d_in[9];  const float* be = (const float*)d_in[10];
  const float* Wsk = (const float*)d_in[11]; const float* bsk = (const float*)d_in[12];
  const float* W1  = (const float*)d_in[13]; const float* b1 = (const float*)d_in[14];
  const float* W2  = (const float*)d_in[15]; const float* b2 = (const float*)d_in[16];
  const float* g1  = (const float*)d_in[17]; const float* lb1 = (const float*)d_in[18];
  const float* g2  = (const float*)d_in[19]; const float* lb2 = (const float*)d_in[20];

  char* ws = (char*)d_ws;
  f16*   Qn     = (f16*)(ws + 0);              // 12.8M
  f16*   Kn     = (f16*)(ws + 12800000L);      // 12.8M
  f16*   Vn     = (f16*)(ws + 25600000L);      // 12.8M
  float* Skip   = (float*)(ws + 38400000L);    // 25.6M -> 64,000,000
  int*   offs   = (int*)(ws + 64000000L);      // 200,192
  int*   cursor = (int*)(ws + 64200192L);      // 200,192
  int*   counts = (int*)(ws + 64429568L);      // 200,000
  int*   bsum   = (int*)(ws + 64629760L);      // 512 B
  int*   boff   = bsum + 64;
  int*   elist  = (int*)(ws + 64630272L);      // 3.2M
  int*   srcs   = (int*)(ws + 67830272L);      // 3.2M
  f16*   emat   = (f16*)(ws + 71030272L);      // 204.8M (dst-sorted)
  float* node1  = (float*)(ws + 275830272L);   // 25.6M
  f16*   WhAll  = (f16*)(ws + 301430272L);     // 229,376 own slot

  (void)hipMemsetAsync(counts, 0, N_NODES * sizeof(int), stream);
  hist_conv_k<<<1024, 256, 0, stream>>>(ei, counts, Wq, Wk, Wv, Wsk, We, W1, W2, WhAll);
  blocksum_k<<<SCAN_NB, 1024, 0, stream>>>(counts, bsum);
  scan_small<<<1, 64, 0, stream>>>(bsum, boff, offs);
  expand_k<<<SCAN_NB, 1024, 0, stream>>>(counts, boff, offs, cursor);
  scatter_k<<<1024, 256, 0, stream>>>(ei, cursor, elist, srcs);

  big_gemms<<<NODE_TILES + EDGE_TILES, 512, 0, stream>>>(
      x0, ea, elist, WhAll, bq, bk, bv, bsk, be, Qn, Kn, Vn, Skip, emat);
  attn_ln<<<12500, 256, 0, stream>>>(offs, srcs, emat, Qn, Kn, Vn, Skip, x0, g1, lb1, node1);
  mlp_ln<<<NODE_TILES, 256, 0, stream>>>(node1, WhAll + 5 * 16384, b1,
                                         WhAll + 6 * 16384, b2, g2, lb2, (float*)d_out);
}